// Round 5
// baseline (5453.262 us; speedup 1.0000x reference)
//
#include <hip/hip_runtime.h>
#include <hip/hip_bf16.h>
#include <cstdint>
#include <cstddef>

// B=32, T=512, I=H=1024, L=2, gates 4H=4096. fp32 in/out.
// d_out fp32: outputs[32][512][1024] ++ h_n[2][32][1024] ++ c_n[2][32][1024].
// Per chunk of Tc steps:
//   gemm128: G0 = x@Wx0^T + b0 (bf16 MFMA, fp32 out; Wx0 pre-cast bf16)
//   lstm_persist (cooperative for co-residency; flag-sync, no grid.sync):
//     ARRIVAL-ORDERED staging: each thread polls its assigned producer's flag
//     and stages that 512B-1KB slice immediately (straggler overlap),
//     weights pinned in registers via asm barrier (compiler can't re-sink),
//     epilogue: LDS repack -> wave0-only packed ring store -> wave-local
//     vmcnt drain -> flag; OUT/h_n stores after the flag (off critical path).

typedef unsigned short ush;
typedef short bf16x8 __attribute__((ext_vector_type(8)));
typedef float f32x4 __attribute__((ext_vector_type(4)));
typedef unsigned long long u64;

#define TT 512
#define NA 64
#define NB 128
#define RING 8

__device__ __forceinline__ ush f2bf(float f) {
  __hip_bfloat16 h = __float2bfloat16(f);
  return *reinterpret_cast<ush*>(&h);
}
__device__ __forceinline__ float sigm(float x) { return 1.f / (1.f + __expf(-x)); }

__device__ __forceinline__ unsigned int aload(const unsigned int* p) {
  return __hip_atomic_load(p, __ATOMIC_RELAXED, __HIP_MEMORY_SCOPE_AGENT);
}
__device__ __forceinline__ void astore(unsigned int* p, unsigned int v) {
  __hip_atomic_store(p, v, __ATOMIC_RELAXED, __HIP_MEMORY_SCOPE_AGENT);
}
__device__ __forceinline__ u64 aload64(const u64* p) {
  return __hip_atomic_load(p, __ATOMIC_RELAXED, __HIP_MEMORY_SCOPE_AGENT);
}
__device__ __forceinline__ void astore64(u64* p, u64 v) {
  __hip_atomic_store(p, v, __ATOMIC_RELAXED, __HIP_MEMORY_SCOPE_AGENT);
}

// ---------------------------------------------------------------------------
// Wb[j][k] = bf16(W[j][off+k]), 1024 cols (plain layout, for gemm128 B).
// ---------------------------------------------------------------------------
__global__ __launch_bounds__(256) void cast_w1k(const float* __restrict__ W,
                                                ush* __restrict__ Wb, int off) {
  int j = blockIdx.x;
  int k = threadIdx.x * 4;
  float4 v = *(const float4*)(W + (size_t)j * 2048 + off + k);
  ushort4 o;
  o.x = f2bf(v.x); o.y = f2bf(v.y); o.z = f2bf(v.z); o.w = f2bf(v.w);
  *(ushort4*)(Wb + (size_t)j * 1024 + k) = o;
}

// ---------------------------------------------------------------------------
// Pre-swizzle W0 h-half into per-(block,wave,chunk,lane) fragment order.
// ---------------------------------------------------------------------------
__global__ __launch_bounds__(256) void swz0(const float* __restrict__ W,
                                            ush* __restrict__ D) {
  int n = blockIdx.x * 256 + threadIdx.x;
  int lane = n & 63, ch = (n >> 6) & 15, w = (n >> 10) & 7, i = n >> 13;
  int l15 = lane & 15, quad = lane >> 4, g = w & 3, kh = w >> 2;
  int row = g * 1024 + i * 16 + l15;
  int col = 1024 + kh * 512 + ch * 32 + quad * 8;
  const float* src = W + (size_t)row * 2048 + col;
  float4 v0 = ((const float4*)src)[0];
  float4 v1 = ((const float4*)src)[1];
  ushort4 o0, o1;
  o0.x = f2bf(v0.x); o0.y = f2bf(v0.y); o0.z = f2bf(v0.z); o0.w = f2bf(v0.w);
  o1.x = f2bf(v1.x); o1.y = f2bf(v1.y); o1.z = f2bf(v1.z); o1.w = f2bf(v1.w);
  *(ushort4*)(D + (size_t)n * 8) = o0;
  *(ushort4*)(D + (size_t)n * 8 + 4) = o1;
}

// ---------------------------------------------------------------------------
// Pre-swizzle W1 (full K=2048). j=n>>13 (128 blocks).
// ---------------------------------------------------------------------------
__global__ __launch_bounds__(256) void swz1(const float* __restrict__ W,
                                            ush* __restrict__ D) {
  int n = blockIdx.x * 256 + threadIdx.x;
  int lane = n & 63, ch = (n >> 6) & 15, w = (n >> 10) & 7, j = n >> 13;
  int l15 = lane & 15, quad = lane >> 4, rh = w & 1, kq = w >> 1;
  int r32 = rh * 16 + l15;
  int row = (r32 >> 3) * 1024 + j * 8 + (r32 & 7);
  int col = kq * 512 + ch * 32 + quad * 8;
  const float* src = W + (size_t)row * 2048 + col;
  float4 v0 = ((const float4*)src)[0];
  float4 v1 = ((const float4*)src)[1];
  ushort4 o0, o1;
  o0.x = f2bf(v0.x); o0.y = f2bf(v0.y); o0.z = f2bf(v0.z); o0.w = f2bf(v0.w);
  o1.x = f2bf(v1.x); o1.y = f2bf(v1.y); o1.z = f2bf(v1.z); o1.w = f2bf(v1.w);
  *(ushort4*)(D + (size_t)n * 8) = o0;
  *(ushort4*)(D + (size_t)n * 8 + 4) = o1;
}

__global__ __launch_bounds__(256) void zeroreg(uint4* __restrict__ p) {
  p[blockIdx.x * 256 + threadIdx.x] = uint4{0, 0, 0, 0};
}

// ---------------------------------------------------------------------------
// 128x128 MFMA GEMM: G[r][j] = bias[j] + sum_k A[r][k]*Wb[j][k]. (unchanged)
// ---------------------------------------------------------------------------
__global__ __launch_bounds__(256) void gemm128(
    const float* __restrict__ xA, const ush* __restrict__ Wb,
    const float* __restrict__ bias, float* __restrict__ G, int t0) {
  __shared__ ush As[128][88];
  __shared__ ush Bs[128][88];
  int tid = threadIdx.x;
  int bn = blockIdx.x, bm = blockIdx.y;
  int srow = tid >> 1;
  int shalf = (tid & 1) * 32;
  int lane = tid & 63, quad = lane >> 4, l15 = lane & 15;
  int w = tid >> 6;
  int m_base = (w >> 1) * 64, n_base = (w & 1) * 64;

  int r = bm * 128 + srow;
  const float* axf = xA + ((size_t)(r & 31) * TT + t0 + (r >> 5)) * 1024;
  const ush* wrow = Wb + (size_t)(bn * 128 + srow) * 1024;

  f32x4 acc[4][4];
#pragma unroll
  for (int i = 0; i < 4; ++i)
#pragma unroll
    for (int j = 0; j < 4; ++j) acc[i][j] = f32x4{0.f, 0.f, 0.f, 0.f};

  for (int k0 = 0; k0 < 1024; k0 += 64) {
    {
      const float* p = axf + k0 + shalf;
      ush* d = &As[srow][shalf];
#pragma unroll
      for (int s = 0; s < 8; ++s) {
        float4 v = ((const float4*)p)[s];
        ushort4 o;
        o.x = f2bf(v.x); o.y = f2bf(v.y); o.z = f2bf(v.z); o.w = f2bf(v.w);
        ((ushort4*)d)[s] = o;
      }
    }
    {
      const uint4* p = (const uint4*)(wrow + k0 + shalf);
      uint4* d = (uint4*)&Bs[srow][shalf];
#pragma unroll
      for (int s = 0; s < 4; ++s) d[s] = p[s];
    }
    __syncthreads();
#pragma unroll
    for (int kc = 0; kc < 2; ++kc) {
      bf16x8 af[4], bf_[4];
#pragma unroll
      for (int i = 0; i < 4; ++i)
        af[i] = *(const bf16x8*)&As[m_base + i * 16 + l15][kc * 32 + quad * 8];
#pragma unroll
      for (int j = 0; j < 4; ++j)
        bf_[j] = *(const bf16x8*)&Bs[n_base + j * 16 + l15][kc * 32 + quad * 8];
#pragma unroll
      for (int i = 0; i < 4; ++i)
#pragma unroll
        for (int j = 0; j < 4; ++j)
          acc[i][j] = __builtin_amdgcn_mfma_f32_16x16x32_bf16(af[i], bf_[j],
                                                              acc[i][j], 0, 0, 0);
    }
    __syncthreads();
  }

#pragma unroll
  for (int j = 0; j < 4; ++j) {
    int col = bn * 128 + n_base + j * 16 + l15;
    float bj = bias[col];
#pragma unroll
    for (int i = 0; i < 4; ++i) {
      int row = bm * 128 + m_base + i * 16 + quad * 4;
#pragma unroll
      for (int reg = 0; reg < 4; ++reg)
        G[(size_t)(row + reg) * 4096 + col] = acc[i][j][reg] + bj;
    }
  }
}

// ---------------------------------------------------------------------------
// Persistent flag-synced recurrence for one chunk of Tc steps.
// 192 blocks x 512 thr, cooperative launch (co-residency only; no grid.sync).
// ---------------------------------------------------------------------------
__global__ __launch_bounds__(512, 2) void lstm_persist(
    const float* __restrict__ G0, const ush* __restrict__ Wsw0,
    const ush* __restrict__ Wsw1, const float* __restrict__ b1,
    ush* __restrict__ h0r, ush* __restrict__ h1r,
    unsigned int* __restrict__ flg,  // prog0 @ [i*16]; prog1 @ [1024 + j*16]
    float* __restrict__ cst, float* __restrict__ OUT,
    float* __restrict__ hno, float* __restrict__ cno,
    int t0, int Tc, int last) {
  __shared__ ush hbuf[65536];       // 128 KB (layer-0 uses first 64 KB)
  __shared__ float pg[8][32][20];   // padded partial-gate exchange
  __shared__ __align__(16) ush hrp[512];  // h repack buffer
  char* hb = (char*)hbuf;

  int tid = threadIdx.x;
  int bid = blockIdx.x;
  int w = tid >> 6, lane = tid & 63, quad = lane >> 4, l15 = lane & 15;
  unsigned int* prog0 = flg;
  unsigned int* prog1 = flg + 1024;

  if (bid < NA) {
    // ================= layer-0 block: 16 cols x 4 gates, K=1024 ============
    int c0 = bid * 16;
    const ush* wp = Wsw0 + ((size_t)bid * 8 + w) * 8192 + (size_t)lane * 8;
    bf16x8 wreg[16];
#pragma unroll
    for (int ch = 0; ch < 16; ++ch) wreg[ch] = *(const bf16x8*)(wp + ch * 512);
#pragma unroll
    for (int ch = 0; ch < 16; ++ch) asm volatile("" : "+v"(wreg[ch]));
    int b = tid >> 4, c = tid & 15;
    int ci = b * 1024 + c0 + c;
    float creg = (t0 > 0) ? cst[ci] : 0.f;
    int m1c = t0;  // cached min(prog1) lower bound (per wave)
    int kbase = (w >> 2) * 1024 + quad * 16;
    int x0 = (l15 & 7) << 4;
    const char* a0p = hb + l15 * 2048;
    const char* a1p = hb + (16 + l15) * 2048;
    int sp_ = tid >> 3, ssub = tid & 7;  // staging: producer, row-group

    for (int s = 0; s < Tc; ++s) {
      int t = t0 + s;
      const float* grow = G0 + (size_t)(s * 32 + b) * 4096 + c0 + c;
      float g0v = grow[0], g1v = grow[1024], g2v = grow[2048], g3v = grow[3072];
      // ring-clobber guard (lazy, per wave)
      while (m1c < t - (RING - 1)) {
        int m = (int)aload(&prog1[lane * 16]);
        m = min(m, (int)aload(&prog1[(64 + lane) * 16]));
#pragma unroll
        for (int d = 1; d < 64; d <<= 1) m = min(m, __shfl_xor(m, d));
        m1c = m;
        if (m1c < t - (RING - 1)) __builtin_amdgcn_s_sleep(2);
      }
      {  // arrival-ordered stage of h0[t-1]: this thread owns producer sp_
        if ((int)aload(&prog0[sp_ * 16]) < t) {
          do { __builtin_amdgcn_s_sleep(1); } while ((int)aload(&prog0[sp_ * 16]) < t);
        }
        const ush* slot = h0r + (size_t)((t - 1) & (RING - 1)) * 32768;
#pragma unroll
        for (int rr = 0; rr < 4; ++rr) {
          int row = ssub * 4 + rr;
          const u64* s2 = (const u64*)(slot + (size_t)row * 1024 + sp_ * 16);
          u64 a0 = aload64(s2), a1 = aload64(s2 + 1);
          u64 a2 = aload64(s2 + 2), a3 = aload64(s2 + 3);
          int x = (row & 7) << 4;
          u64* d0 = (u64*)(hb + row * 2048 + ((sp_ * 32) ^ x));
          d0[0] = a0; d0[1] = a1;
          u64* d1 = (u64*)(hb + row * 2048 + ((sp_ * 32 + 16) ^ x));
          d1[0] = a2; d1[1] = a3;
        }
      }
      __syncthreads();
      f32x4 acc0 = {0.f, 0.f, 0.f, 0.f}, acc1 = {0.f, 0.f, 0.f, 0.f};
#pragma unroll
      for (int ch = 0; ch < 16; ++ch) {
        int kb = kbase + ch * 64;
        bf16x8 a0 = *(const bf16x8*)(a0p + (kb ^ x0));
        bf16x8 a1 = *(const bf16x8*)(a1p + (kb ^ x0));
        acc0 = __builtin_amdgcn_mfma_f32_16x16x32_bf16(a0, wreg[ch], acc0, 0, 0, 0);
        acc1 = __builtin_amdgcn_mfma_f32_16x16x32_bf16(a1, wreg[ch], acc1, 0, 0, 0);
      }
#pragma unroll
      for (int reg = 0; reg < 4; ++reg) {
        pg[w][quad * 4 + reg][l15] = acc0[reg];
        pg[w][16 + quad * 4 + reg][l15] = acc1[reg];
      }
      __syncthreads();
      float s0 = g0v + pg[0][b][c] + pg[4][b][c];
      float s1 = g1v + pg[1][b][c] + pg[5][b][c];
      float s2 = g2v + pg[2][b][c] + pg[6][b][c];
      float s3 = g3v + pg[3][b][c] + pg[7][b][c];
      float fg = sigm(s0), ig = sigm(s1), gv = tanhf(s2), og = sigm(s3);
      creg = fg * creg + ig * gv;
      float hnv = og * tanhf(creg);
      hrp[b * 16 + c] = f2bf(hnv);
      __syncthreads();
      if (w == 0) {  // wave0: packed ring store + wave-local drain + flag
        int row = lane >> 1, half = lane & 1;
        const u64* sp2 = (const u64*)&hrp[row * 16 + half * 8];
        u64 d0 = sp2[0], d1 = sp2[1];
        u64* dp = (u64*)(h0r + (size_t)(t & (RING - 1)) * 32768 +
                         (size_t)row * 1024 + c0 + half * 8);
        astore64(dp, d0);
        astore64(dp + 1, d1);
        asm volatile("s_waitcnt vmcnt(0)" ::: "memory");
        if (tid == 0) astore(&prog0[bid * 16], (unsigned int)(t + 1));
      }
      if (t == TT - 1) hno[ci] = hnv;
    }
    cst[ci] = creg;
    if (last) cno[ci] = creg;
  } else {
    // ============ layer-1 block: 8 cols x 4 gates, K=2048 (h0 ++ h1) =======
    int jb = bid - NA;
    int c0b = jb * 8;
    const ush* wp = Wsw1 + ((size_t)jb * 8 + w) * 8192 + (size_t)lane * 8;
    bf16x8 wreg[16];
#pragma unroll
    for (int ch = 0; ch < 16; ++ch) wreg[ch] = *(const bf16x8*)(wp + ch * 512);
#pragma unroll
    for (int ch = 0; ch < 16; ++ch) asm volatile("" : "+v"(wreg[ch]));
    bool pw = tid < 256;
    int b = tid >> 3, cc = tid & 7;
    int ci = b * 1024 + c0b + cc;  // meaningful only when pw
    float creg = 0.f;
    float biasr[4] = {0.f, 0.f, 0.f, 0.f};
    if (pw) {
      creg = (t0 > 0) ? cst[32768 + ci] : 0.f;
#pragma unroll
      for (int g = 0; g < 4; ++g) biasr[g] = b1[g * 1024 + c0b + cc];
    }
    int kq = w >> 1;
    int boff = (kq < 2) ? 0 : 65536;
    int kbase = (kq & 1) * 1024 + quad * 16;
    int x0 = (l15 & 7) << 4;
    const char* a0p = hb + boff + l15 * 2048;
    const char* a1p = a0p + 16 * 2048;
    int p0_ = tid >> 3, s0sub = tid & 7;  // h0 staging: 64 producers x 8 thr
    int p1_ = tid >> 2, s1sub = tid & 3;  // h1 staging: 128 producers x 4 thr

    for (int s = 0; s < Tc; ++s) {
      int t = t0 + s;
      {  // arrival-ordered stage of h0[t] (producer = L0 block p0_)
        if ((int)aload(&prog0[p0_ * 16]) < t + 1) {
          do { __builtin_amdgcn_s_sleep(1); } while ((int)aload(&prog0[p0_ * 16]) < t + 1);
        }
        const ush* slot = h0r + (size_t)(t & (RING - 1)) * 32768;
#pragma unroll
        for (int rr = 0; rr < 4; ++rr) {
          int row = s0sub * 4 + rr;
          const u64* s2 = (const u64*)(slot + (size_t)row * 1024 + p0_ * 16);
          u64 a0 = aload64(s2), a1 = aload64(s2 + 1);
          u64 a2 = aload64(s2 + 2), a3 = aload64(s2 + 3);
          int x = (row & 7) << 4;
          u64* d0 = (u64*)(hb + row * 2048 + ((p0_ * 32) ^ x));
          d0[0] = a0; d0[1] = a1;
          u64* d1 = (u64*)(hb + row * 2048 + ((p0_ * 32 + 16) ^ x));
          d1[0] = a2; d1[1] = a3;
        }
      }
      {  // arrival-ordered stage of h1[t-1] (producer = L1 block p1_)
        if ((int)aload(&prog1[p1_ * 16]) < t) {
          do { __builtin_amdgcn_s_sleep(1); } while ((int)aload(&prog1[p1_ * 16]) < t);
        }
        const ush* slot = h1r + (size_t)((t - 1) & (RING - 1)) * 32768;
#pragma unroll
        for (int rr = 0; rr < 8; ++rr) {
          int row = s1sub * 8 + rr;
          const u64* s2 = (const u64*)(slot + (size_t)row * 1024 + p1_ * 8);
          u64 a0 = aload64(s2), a1 = aload64(s2 + 1);
          u64* d0 = (u64*)(hb + 65536 + row * 2048 + ((p1_ * 16) ^ ((row & 7) << 4)));
          d0[0] = a0; d0[1] = a1;
        }
      }
      __syncthreads();
      f32x4 acc0 = {0.f, 0.f, 0.f, 0.f}, acc1 = {0.f, 0.f, 0.f, 0.f};
#pragma unroll
      for (int ch = 0; ch < 16; ++ch) {
        int kb = kbase + ch * 64;
        bf16x8 a0 = *(const bf16x8*)(a0p + (kb ^ x0));
        bf16x8 a1 = *(const bf16x8*)(a1p + (kb ^ x0));
        acc0 = __builtin_amdgcn_mfma_f32_16x16x32_bf16(a0, wreg[ch], acc0, 0, 0, 0);
        acc1 = __builtin_amdgcn_mfma_f32_16x16x32_bf16(a1, wreg[ch], acc1, 0, 0, 0);
      }
#pragma unroll
      for (int reg = 0; reg < 4; ++reg) {
        pg[w][quad * 4 + reg][l15] = acc0[reg];
        pg[w][16 + quad * 4 + reg][l15] = acc1[reg];
      }
      __syncthreads();
      float hnv = 0.f;
      if (pw) {
        float sg[4];
#pragma unroll
        for (int g = 0; g < 4; ++g) {
          int r = g * 8 + cc, rrh = r >> 4, ri = r & 15;
          sg[g] = biasr[g] + pg[rrh][b][ri] + pg[2 + rrh][b][ri] +
                  pg[4 + rrh][b][ri] + pg[6 + rrh][b][ri];
        }
        float fg = sigm(sg[0]), ig = sigm(sg[1]), gv = tanhf(sg[2]),
              og = sigm(sg[3]);
        creg = fg * creg + ig * gv;
        hnv = og * tanhf(creg);
        hrp[b * 8 + cc] = f2bf(hnv);
      }
      __syncthreads();
      if (w == 0) {  // wave0: packed ring store + wave-local drain + flag
        int row = lane >> 1, half = lane & 1;
        u64 d0 = *(const u64*)&hrp[row * 8 + half * 4];
        u64* dp = (u64*)(h1r + (size_t)(t & (RING - 1)) * 32768 +
                         (size_t)row * 1024 + c0b + half * 4);
        astore64(dp, d0);
        asm volatile("s_waitcnt vmcnt(0)" ::: "memory");
        if (tid == 0) astore(&prog1[jb * 16], (unsigned int)(t + 1));
      }
      if (pw) {
        OUT[((size_t)b * TT + t) * 1024 + c0b + cc] = hnv;
        if (t == TT - 1) hno[32768 + ci] = hnv;
      }
    }
    if (pw) {
      cst[32768 + ci] = creg;
      if (last) cno[32768 + ci] = creg;
    }
  }
}

extern "C" void kernel_launch(void* const* d_in, const int* in_sizes, int n_in,
                              void* d_out, int out_size, void* d_ws, size_t ws_size,
                              hipStream_t stream) {
  const float* x = (const float*)d_in[0];
  const float* W0 = (const float*)d_in[1];
  const float* b0 = (const float*)d_in[2];
  const float* W1 = (const float*)d_in[3];
  const float* b1 = (const float*)d_in[4];
  float* OUT = (float*)d_out;

  // ws layout (bytes):
  //   Wxb0 [4096][1024] bf16 : 0        (gemm B, x-half of W0)
  //   Wsw0 swizzled 8 MB     : 8388608
  //   Wsw1 swizzled 16 MB    : 16777216
  //   h0r  RINGx64KB         : 33554432
  //   h1r  RINGx64KB         : 34078720
  //   flg  16 KB             : 34603008
  //   cst  [2][32][1024] f32 : 34619392
  //   G0   [Tc*32][4096] f32 : 34881536
  int Tc = 4;
  {
    const int cand[8] = {512, 256, 128, 64, 32, 16, 8, 4};
    for (int i = 0; i < 8; ++i) {
      size_t need = 34881536ull + (size_t)cand[i] * 524288;
      if (need <= ws_size) { Tc = cand[i]; break; }
    }
  }
  char* ws = (char*)d_ws;
  ush* Wxb0 = (ush*)ws;
  ush* Wsw0 = (ush*)(ws + 8388608);
  ush* Wsw1 = (ush*)(ws + 16777216);
  ush* h0r = (ush*)(ws + 33554432);
  ush* h1r = (ush*)(ws + 34078720);
  unsigned int* flg = (unsigned int*)(ws + 34603008);
  float* cst = (float*)(ws + 34619392);
  float* G = (float*)(ws + 34881536);

  cast_w1k<<<4096, 256, 0, stream>>>(W0, Wxb0, 0);
  swz0<<<2048, 256, 0, stream>>>(W0, Wsw0);
  swz1<<<4096, 256, 0, stream>>>(W1, Wsw1);
  zeroreg<<<260, 256, 0, stream>>>((uint4*)(ws + 33554432));  // rings + flags

  float* hnp = OUT + 16777216;
  float* cnp = OUT + 16777216 + 65536;
  dim3 ggrid(32, (unsigned)(Tc * 32 / 128));

  const int NCH = TT / Tc;
  for (int ch = 0; ch < NCH; ++ch) {
    int t0v = ch * Tc;
    int lastv = (ch == NCH - 1) ? 1 : 0;
    gemm128<<<ggrid, 256, 0, stream>>>(x, Wxb0, b0, G, t0v);
    void* pargs[14] = {(void*)&G,    (void*)&Wsw0, (void*)&Wsw1, (void*)&b1,
                       (void*)&h0r,  (void*)&h1r,  (void*)&flg,  (void*)&cst,
                       (void*)&OUT,  (void*)&hnp,  (void*)&cnp,  (void*)&t0v,
                       (void*)&Tc,   (void*)&lastv};
    hipLaunchCooperativeKernel((void*)lstm_persist, dim3(NA + NB), dim3(512),
                               pargs, 0, stream);
  }
}

// Round 6
// 3868.698 us; speedup vs baseline: 1.4096x; 1.4096x over previous
//
#include <hip/hip_runtime.h>
#include <hip/hip_bf16.h>
#include <cstdint>
#include <cstddef>

// B=32, T=512, I=H=1024, L=2, gates 4H=4096. fp32 in/out.
// d_out fp32: outputs[32][512][1024] ++ h_n[2][32][1024] ++ c_n[2][32][1024].
// Per chunk of Tc steps:
//   gemm128: G0 = x@Wx0^T + b0 (bf16 MFMA, fp32 out; Wx0 pre-cast bf16)
//   lstm_persist (cooperative for co-residency; flag-sync, no grid.sync):
//     AGGREGATED arrival counters: one monotonic counter per layer per
//     ring slot (cnt[t&15], 128B-spaced lines). Producers: single
//     fire-and-forget agent atomicAdd after drain barrier. Consumers:
//     tid0-only poll of ONE line -> __syncthreads broadcast. ~64x less
//     flag traffic than per-block flags (which contended L3).
//     Weights pinned in registers; h via 8-deep rings (sc atomics);
//     b128 conflict-free LDS staging; pg padded [20].

typedef unsigned short ush;
typedef short bf16x8 __attribute__((ext_vector_type(8)));
typedef float f32x4 __attribute__((ext_vector_type(4)));
typedef unsigned long long u64;

#define TT 512
#define NA 64
#define NB 128
#define RING 8

__device__ __forceinline__ ush f2bf(float f) {
  __hip_bfloat16 h = __float2bfloat16(f);
  return *reinterpret_cast<ush*>(&h);
}
__device__ __forceinline__ float sigm(float x) { return 1.f / (1.f + __expf(-x)); }

__device__ __forceinline__ unsigned int aload(const unsigned int* p) {
  return __hip_atomic_load(p, __ATOMIC_RELAXED, __HIP_MEMORY_SCOPE_AGENT);
}
__device__ __forceinline__ void aadd(unsigned int* p) {
  (void)__hip_atomic_fetch_add(p, 1u, __ATOMIC_RELAXED, __HIP_MEMORY_SCOPE_AGENT);
}
__device__ __forceinline__ void astore(unsigned int* p, unsigned int v) {
  __hip_atomic_store(p, v, __ATOMIC_RELAXED, __HIP_MEMORY_SCOPE_AGENT);
}
__device__ __forceinline__ u64 aload64(const u64* p) {
  return __hip_atomic_load(p, __ATOMIC_RELAXED, __HIP_MEMORY_SCOPE_AGENT);
}

// ---------------------------------------------------------------------------
// Wb[j][k] = bf16(W[j][off+k]), 1024 cols (plain layout, for gemm128 B).
// ---------------------------------------------------------------------------
__global__ __launch_bounds__(256) void cast_w1k(const float* __restrict__ W,
                                                ush* __restrict__ Wb, int off) {
  int j = blockIdx.x;
  int k = threadIdx.x * 4;
  float4 v = *(const float4*)(W + (size_t)j * 2048 + off + k);
  ushort4 o;
  o.x = f2bf(v.x); o.y = f2bf(v.y); o.z = f2bf(v.z); o.w = f2bf(v.w);
  *(ushort4*)(Wb + (size_t)j * 1024 + k) = o;
}

// ---------------------------------------------------------------------------
// Pre-swizzle W0 h-half into per-(block,wave,chunk,lane) fragment order.
// ---------------------------------------------------------------------------
__global__ __launch_bounds__(256) void swz0(const float* __restrict__ W,
                                            ush* __restrict__ D) {
  int n = blockIdx.x * 256 + threadIdx.x;
  int lane = n & 63, ch = (n >> 6) & 15, w = (n >> 10) & 7, i = n >> 13;
  int l15 = lane & 15, quad = lane >> 4, g = w & 3, kh = w >> 2;
  int row = g * 1024 + i * 16 + l15;
  int col = 1024 + kh * 512 + ch * 32 + quad * 8;
  const float* src = W + (size_t)row * 2048 + col;
  float4 v0 = ((const float4*)src)[0];
  float4 v1 = ((const float4*)src)[1];
  ushort4 o0, o1;
  o0.x = f2bf(v0.x); o0.y = f2bf(v0.y); o0.z = f2bf(v0.z); o0.w = f2bf(v0.w);
  o1.x = f2bf(v1.x); o1.y = f2bf(v1.y); o1.z = f2bf(v1.z); o1.w = f2bf(v1.w);
  *(ushort4*)(D + (size_t)n * 8) = o0;
  *(ushort4*)(D + (size_t)n * 8 + 4) = o1;
}

// ---------------------------------------------------------------------------
// Pre-swizzle W1 (full K=2048). j=n>>13 (128 blocks).
// ---------------------------------------------------------------------------
__global__ __launch_bounds__(256) void swz1(const float* __restrict__ W,
                                            ush* __restrict__ D) {
  int n = blockIdx.x * 256 + threadIdx.x;
  int lane = n & 63, ch = (n >> 6) & 15, w = (n >> 10) & 7, j = n >> 13;
  int l15 = lane & 15, quad = lane >> 4, rh = w & 1, kq = w >> 1;
  int r32 = rh * 16 + l15;
  int row = (r32 >> 3) * 1024 + j * 8 + (r32 & 7);
  int col = kq * 512 + ch * 32 + quad * 8;
  const float* src = W + (size_t)row * 2048 + col;
  float4 v0 = ((const float4*)src)[0];
  float4 v1 = ((const float4*)src)[1];
  ushort4 o0, o1;
  o0.x = f2bf(v0.x); o0.y = f2bf(v0.y); o0.z = f2bf(v0.z); o0.w = f2bf(v0.w);
  o1.x = f2bf(v1.x); o1.y = f2bf(v1.y); o1.z = f2bf(v1.z); o1.w = f2bf(v1.w);
  *(ushort4*)(D + (size_t)n * 8) = o0;
  *(ushort4*)(D + (size_t)n * 8 + 4) = o1;
}

__global__ __launch_bounds__(256) void zeroreg(uint4* __restrict__ p) {
  p[blockIdx.x * 256 + threadIdx.x] = uint4{0, 0, 0, 0};
}

// ---------------------------------------------------------------------------
// 128x128 MFMA GEMM: G[r][j] = bias[j] + sum_k A[r][k]*Wb[j][k]. (unchanged)
// ---------------------------------------------------------------------------
__global__ __launch_bounds__(256) void gemm128(
    const float* __restrict__ xA, const ush* __restrict__ Wb,
    const float* __restrict__ bias, float* __restrict__ G, int t0) {
  __shared__ ush As[128][88];
  __shared__ ush Bs[128][88];
  int tid = threadIdx.x;
  int bn = blockIdx.x, bm = blockIdx.y;
  int srow = tid >> 1;
  int shalf = (tid & 1) * 32;
  int lane = tid & 63, quad = lane >> 4, l15 = lane & 15;
  int w = tid >> 6;
  int m_base = (w >> 1) * 64, n_base = (w & 1) * 64;

  int r = bm * 128 + srow;
  const float* axf = xA + ((size_t)(r & 31) * TT + t0 + (r >> 5)) * 1024;
  const ush* wrow = Wb + (size_t)(bn * 128 + srow) * 1024;

  f32x4 acc[4][4];
#pragma unroll
  for (int i = 0; i < 4; ++i)
#pragma unroll
    for (int j = 0; j < 4; ++j) acc[i][j] = f32x4{0.f, 0.f, 0.f, 0.f};

  for (int k0 = 0; k0 < 1024; k0 += 64) {
    {
      const float* p = axf + k0 + shalf;
      ush* d = &As[srow][shalf];
#pragma unroll
      for (int s = 0; s < 8; ++s) {
        float4 v = ((const float4*)p)[s];
        ushort4 o;
        o.x = f2bf(v.x); o.y = f2bf(v.y); o.z = f2bf(v.z); o.w = f2bf(v.w);
        ((ushort4*)d)[s] = o;
      }
    }
    {
      const uint4* p = (const uint4*)(wrow + k0 + shalf);
      uint4* d = (uint4*)&Bs[srow][shalf];
#pragma unroll
      for (int s = 0; s < 4; ++s) d[s] = p[s];
    }
    __syncthreads();
#pragma unroll
    for (int kc = 0; kc < 2; ++kc) {
      bf16x8 af[4], bf_[4];
#pragma unroll
      for (int i = 0; i < 4; ++i)
        af[i] = *(const bf16x8*)&As[m_base + i * 16 + l15][kc * 32 + quad * 8];
#pragma unroll
      for (int j = 0; j < 4; ++j)
        bf_[j] = *(const bf16x8*)&Bs[n_base + j * 16 + l15][kc * 32 + quad * 8];
#pragma unroll
      for (int i = 0; i < 4; ++i)
#pragma unroll
        for (int j = 0; j < 4; ++j)
          acc[i][j] = __builtin_amdgcn_mfma_f32_16x16x32_bf16(af[i], bf_[j],
                                                              acc[i][j], 0, 0, 0);
    }
    __syncthreads();
  }

#pragma unroll
  for (int j = 0; j < 4; ++j) {
    int col = bn * 128 + n_base + j * 16 + l15;
    float bj = bias[col];
#pragma unroll
    for (int i = 0; i < 4; ++i) {
      int row = bm * 128 + m_base + i * 16 + quad * 4;
#pragma unroll
      for (int reg = 0; reg < 4; ++reg)
        G[(size_t)(row + reg) * 4096 + col] = acc[i][j][reg] + bj;
    }
  }
}

// ---------------------------------------------------------------------------
// Persistent flag-synced recurrence for one chunk of Tc steps.
// 192 blocks x 512 thr, cooperative launch (co-residency only; no grid.sync).
// cnt0 slot s: flg[s*32]; cnt1 slot s: flg[512 + s*32]  (16 slots, 128B apart)
// ---------------------------------------------------------------------------
__global__ __launch_bounds__(512, 2) void lstm_persist(
    const float* __restrict__ G0, const ush* __restrict__ Wsw0,
    const ush* __restrict__ Wsw1, const float* __restrict__ b1,
    ush* __restrict__ h0r, ush* __restrict__ h1r,
    unsigned int* __restrict__ flg,
    float* __restrict__ cst, float* __restrict__ OUT,
    float* __restrict__ hno, float* __restrict__ cno,
    int t0, int Tc, int last) {
  __shared__ ush hbuf[65536];       // 128 KB (layer-0 uses first 64 KB)
  __shared__ float pg[8][32][20];   // padded partial-gate exchange
  char* hb = (char*)hbuf;

  int tid = threadIdx.x;
  int bid = blockIdx.x;
  int w = tid >> 6, lane = tid & 63, quad = lane >> 4, l15 = lane & 15;

  if (bid < NA) {
    // ================= layer-0 block: 16 cols x 4 gates, K=1024 ============
    int c0 = bid * 16;
    const ush* wp = Wsw0 + ((size_t)bid * 8 + w) * 8192 + (size_t)lane * 8;
    bf16x8 wreg[16];
#pragma unroll
    for (int ch = 0; ch < 16; ++ch) wreg[ch] = *(const bf16x8*)(wp + ch * 512);
#pragma unroll
    for (int ch = 0; ch < 16; ++ch) asm volatile("" : "+v"(wreg[ch]));
    int b = tid >> 4, c = tid & 15;
    int ci = b * 1024 + c0 + c;
    float creg = (t0 > 0) ? cst[ci] : 0.f;
    int kbase = (w >> 2) * 1024 + quad * 16;
    int x0 = (l15 & 7) << 4;
    const char* a0p = hb + l15 * 2048;
    const char* a1p = hb + (16 + l15) * 2048;

    for (int s = 0; s < Tc; ++s) {
      int t = t0 + s;
      const float* grow = G0 + (size_t)(s * 32 + b) * 4096 + c0 + c;
      float g0v = grow[0], g1v = grow[1024], g2v = grow[2048], g3v = grow[3072];
      if (tid == 0) {
        if (t > 0) {  // all 64 L0 blocks done step t-1
          unsigned int* cp = &flg[((t - 1) & 15) * 32];
          unsigned int tgt = 64u * ((unsigned)((t - 1) >> 4) + 1u);
          if (aload(cp) < tgt) {
            do { __builtin_amdgcn_s_sleep(2); } while (aload(cp) < tgt);
          }
        }
        if (t - RING >= 0) {  // ring guard: all 128 L1 blocks done step t-8
          unsigned int* cp = &flg[512 + ((t - RING) & 15) * 32];
          unsigned int tgt = 128u * ((unsigned)((t - RING) >> 4) + 1u);
          if (aload(cp) < tgt) {
            do { __builtin_amdgcn_s_sleep(2); } while (aload(cp) < tgt);
          }
        }
      }
      __syncthreads();
      {  // stage h0[t-1] -> swizzled LDS (b128 writes, conflict-free)
        const u64* src = (const u64*)(h0r + (size_t)((t - 1) & (RING - 1)) * 32768);
#pragma unroll
        for (int s2 = 0; s2 < 8; ++s2) {
          int gi = s2 * 512 + tid;
          uint4 v;
          ((u64*)&v)[0] = aload64(src + (size_t)gi * 2);
          ((u64*)&v)[1] = aload64(src + (size_t)gi * 2 + 1);
          int r = gi >> 7, kb = (gi & 127) * 16;
          *(uint4*)(hb + r * 2048 + (kb ^ ((r & 7) << 4))) = v;
        }
      }
      __syncthreads();
      f32x4 acc0 = {0.f, 0.f, 0.f, 0.f}, acc1 = {0.f, 0.f, 0.f, 0.f};
#pragma unroll
      for (int ch = 0; ch < 16; ++ch) {
        int kb = kbase + ch * 64;
        bf16x8 a0 = *(const bf16x8*)(a0p + (kb ^ x0));
        bf16x8 a1 = *(const bf16x8*)(a1p + (kb ^ x0));
        acc0 = __builtin_amdgcn_mfma_f32_16x16x32_bf16(a0, wreg[ch], acc0, 0, 0, 0);
        acc1 = __builtin_amdgcn_mfma_f32_16x16x32_bf16(a1, wreg[ch], acc1, 0, 0, 0);
      }
#pragma unroll
      for (int reg = 0; reg < 4; ++reg) {
        pg[w][quad * 4 + reg][l15] = acc0[reg];
        pg[w][16 + quad * 4 + reg][l15] = acc1[reg];
      }
      __syncthreads();
      float s0 = g0v + pg[0][b][c] + pg[4][b][c];
      float s1 = g1v + pg[1][b][c] + pg[5][b][c];
      float s2 = g2v + pg[2][b][c] + pg[6][b][c];
      float s3 = g3v + pg[3][b][c] + pg[7][b][c];
      float fg = sigm(s0), ig = sigm(s1), gv = tanhf(s2), og = sigm(s3);
      creg = fg * creg + ig * gv;
      float hnv = og * tanhf(creg);
      float ho = __shfl_xor(hnv, 1);
      if (!(tid & 1)) {
        unsigned int pk = (unsigned int)f2bf(hnv) | ((unsigned int)f2bf(ho) << 16);
        ush* slot = h0r + (size_t)(t & (RING - 1)) * 32768;
        astore((unsigned int*)(slot + ci), pk);
      }
      if (t == TT - 1) hno[ci] = hnv;
      __syncthreads();  // drains h stores (vmcnt) before arrival add
      if (tid == 0) aadd(&flg[(t & 15) * 32]);
    }
    cst[ci] = creg;
    if (last) cno[ci] = creg;
  } else {
    // ============ layer-1 block: 8 cols x 4 gates, K=2048 (h0 ++ h1) =======
    int jb = bid - NA;
    int c0b = jb * 8;
    const ush* wp = Wsw1 + ((size_t)jb * 8 + w) * 8192 + (size_t)lane * 8;
    bf16x8 wreg[16];
#pragma unroll
    for (int ch = 0; ch < 16; ++ch) wreg[ch] = *(const bf16x8*)(wp + ch * 512);
#pragma unroll
    for (int ch = 0; ch < 16; ++ch) asm volatile("" : "+v"(wreg[ch]));
    bool pw = tid < 256;
    int b = tid >> 3, cc = tid & 7;
    int ci = b * 1024 + c0b + cc;  // meaningful only when pw
    float creg = 0.f;
    float biasr[4] = {0.f, 0.f, 0.f, 0.f};
    if (pw) {
      creg = (t0 > 0) ? cst[32768 + ci] : 0.f;
#pragma unroll
      for (int g = 0; g < 4; ++g) biasr[g] = b1[g * 1024 + c0b + cc];
    }
    int kq = w >> 1;
    int boff = (kq < 2) ? 0 : 65536;
    int kbase = (kq & 1) * 1024 + quad * 16;
    int x0 = (l15 & 7) << 4;
    const char* a0p = hb + boff + l15 * 2048;
    const char* a1p = a0p + 16 * 2048;

    for (int s = 0; s < Tc; ++s) {
      int t = t0 + s;
      if (tid == 0) {
        {  // h0[t] ready: all 64 L0 blocks done step t
          unsigned int* cp = &flg[(t & 15) * 32];
          unsigned int tgt = 64u * ((unsigned)(t >> 4) + 1u);
          if (aload(cp) < tgt) {
            do { __builtin_amdgcn_s_sleep(2); } while (aload(cp) < tgt);
          }
        }
        if (t > 0) {  // h1[t-1] ready: all 128 L1 blocks done step t-1
          unsigned int* cp = &flg[512 + ((t - 1) & 15) * 32];
          unsigned int tgt = 128u * ((unsigned)((t - 1) >> 4) + 1u);
          if (aload(cp) < tgt) {
            do { __builtin_amdgcn_s_sleep(2); } while (aload(cp) < tgt);
          }
        }
      }
      __syncthreads();
      {  // stage h0[t] and h1[t-1] -> swizzled LDS (b128, conflict-free)
        const u64* s0p = (const u64*)(h0r + (size_t)(t & (RING - 1)) * 32768);
        const u64* s1p = (const u64*)(h1r + (size_t)((t - 1) & (RING - 1)) * 32768);
#pragma unroll
        for (int s2 = 0; s2 < 16; ++s2) {
          const u64* src = (s2 < 8) ? s0p : s1p;
          int gi = (s2 & 7) * 512 + tid;
          uint4 v;
          ((u64*)&v)[0] = aload64(src + (size_t)gi * 2);
          ((u64*)&v)[1] = aload64(src + (size_t)gi * 2 + 1);
          int r = gi >> 7, kb = (gi & 127) * 16;
          *(uint4*)(hb + ((s2 < 8) ? 0 : 65536) + r * 2048 +
                    (kb ^ ((r & 7) << 4))) = v;
        }
      }
      __syncthreads();
      f32x4 acc0 = {0.f, 0.f, 0.f, 0.f}, acc1 = {0.f, 0.f, 0.f, 0.f};
#pragma unroll
      for (int ch = 0; ch < 16; ++ch) {
        int kb = kbase + ch * 64;
        bf16x8 a0 = *(const bf16x8*)(a0p + (kb ^ x0));
        bf16x8 a1 = *(const bf16x8*)(a1p + (kb ^ x0));
        acc0 = __builtin_amdgcn_mfma_f32_16x16x32_bf16(a0, wreg[ch], acc0, 0, 0, 0);
        acc1 = __builtin_amdgcn_mfma_f32_16x16x32_bf16(a1, wreg[ch], acc1, 0, 0, 0);
      }
#pragma unroll
      for (int reg = 0; reg < 4; ++reg) {
        pg[w][quad * 4 + reg][l15] = acc0[reg];
        pg[w][16 + quad * 4 + reg][l15] = acc1[reg];
      }
      __syncthreads();
      float hnv = 0.f;
      if (pw) {
        float sg[4];
#pragma unroll
        for (int g = 0; g < 4; ++g) {
          int r = g * 8 + cc, rrh = r >> 4, ri = r & 15;
          sg[g] = biasr[g] + pg[rrh][b][ri] + pg[2 + rrh][b][ri] +
                  pg[4 + rrh][b][ri] + pg[6 + rrh][b][ri];
        }
        float fg = sigm(sg[0]), ig = sigm(sg[1]), gv = tanhf(sg[2]),
              og = sigm(sg[3]);
        creg = fg * creg + ig * gv;
        hnv = og * tanhf(creg);
        float ho = __shfl_xor(hnv, 1);
        if (!(tid & 1)) {
          unsigned int pk = (unsigned int)f2bf(hnv) | ((unsigned int)f2bf(ho) << 16);
          ush* slot = h1r + (size_t)(t & (RING - 1)) * 32768;
          astore((unsigned int*)(slot + ci), pk);
        }
      }
      __syncthreads();  // drains h stores (vmcnt) before arrival add
      if (tid == 0) aadd(&flg[512 + (t & 15) * 32]);
      if (pw) {  // OUT/h_n off the critical path (after the arrival add)
        OUT[((size_t)b * TT + t) * 1024 + c0b + cc] = hnv;
        if (t == TT - 1) hno[32768 + ci] = hnv;
      }
    }
    if (pw) {
      cst[32768 + ci] = creg;
      if (last) cno[32768 + ci] = creg;
    }
  }
}

extern "C" void kernel_launch(void* const* d_in, const int* in_sizes, int n_in,
                              void* d_out, int out_size, void* d_ws, size_t ws_size,
                              hipStream_t stream) {
  const float* x = (const float*)d_in[0];
  const float* W0 = (const float*)d_in[1];
  const float* b0 = (const float*)d_in[2];
  const float* W1 = (const float*)d_in[3];
  const float* b1 = (const float*)d_in[4];
  float* OUT = (float*)d_out;

  // ws layout (bytes):
  //   Wxb0 [4096][1024] bf16 : 0        (gemm B, x-half of W0)
  //   Wsw0 swizzled 8 MB     : 8388608
  //   Wsw1 swizzled 16 MB    : 16777216
  //   h0r  RINGx64KB         : 33554432
  //   h1r  RINGx64KB         : 34078720
  //   flg  16 KB             : 34603008  (cnt0/cnt1 arrival counters)
  //   cst  [2][32][1024] f32 : 34619392
  //   G0   [Tc*32][4096] f32 : 34881536
  int Tc = 4;
  {
    const int cand[8] = {512, 256, 128, 64, 32, 16, 8, 4};
    for (int i = 0; i < 8; ++i) {
      size_t need = 34881536ull + (size_t)cand[i] * 524288;
      if (need <= ws_size) { Tc = cand[i]; break; }
    }
  }
  char* ws = (char*)d_ws;
  ush* Wxb0 = (ush*)ws;
  ush* Wsw0 = (ush*)(ws + 8388608);
  ush* Wsw1 = (ush*)(ws + 16777216);
  ush* h0r = (ush*)(ws + 33554432);
  ush* h1r = (ush*)(ws + 34078720);
  unsigned int* flg = (unsigned int*)(ws + 34603008);
  float* cst = (float*)(ws + 34619392);
  float* G = (float*)(ws + 34881536);

  cast_w1k<<<4096, 256, 0, stream>>>(W0, Wxb0, 0);
  swz0<<<2048, 256, 0, stream>>>(W0, Wsw0);
  swz1<<<4096, 256, 0, stream>>>(W1, Wsw1);
  zeroreg<<<260, 256, 0, stream>>>((uint4*)(ws + 33554432));  // rings + counters

  float* hnp = OUT + 16777216;
  float* cnp = OUT + 16777216 + 65536;
  dim3 ggrid(32, (unsigned)(Tc * 32 / 128));

  const int NCH = TT / Tc;
  for (int ch = 0; ch < NCH; ++ch) {
    int t0v = ch * Tc;
    int lastv = (ch == NCH - 1) ? 1 : 0;
    gemm128<<<ggrid, 256, 0, stream>>>(x, Wxb0, b0, G, t0v);
    void* pargs[14] = {(void*)&G,    (void*)&Wsw0, (void*)&Wsw1, (void*)&b1,
                       (void*)&h0r,  (void*)&h1r,  (void*)&flg,  (void*)&cst,
                       (void*)&OUT,  (void*)&hnp,  (void*)&cnp,  (void*)&t0v,
                       (void*)&Tc,   (void*)&lastv};
    hipLaunchCooperativeKernel((void*)lstm_persist, dim3(NA + NB), dim3(512),
                               pargs, 0, stream);
  }
}

// Round 7
// 2876.492 us; speedup vs baseline: 1.8958x; 1.3449x over previous
//
#include <hip/hip_runtime.h>
#include <hip/hip_bf16.h>
#include <cstdint>
#include <cstddef>

// B=32, T=512, I=H=1024, L=2, gates 4H=4096. fp32 in/out.
// d_out fp32: outputs[32][512][1024] ++ h_n[2][32][1024] ++ c_n[2][32][1024].
// Per chunk of Tc steps:
//   gemm128: G0 = x@Wx0^T + b0 (bf16 MFMA, fp32 out; Wx0 pre-cast bf16)
//   lstm_persist (cooperative for co-residency; flag-sync, no grid.sync):
//     per-block progress flags (r3 scheme: single relaxed store, wave0
//     lane-parallel poll — no atomic-RMW contention),
//     ring h-exchange via 16B device-scope (sc1) loads/stores:
//       issue-all -> one vmcnt(0) -> sched_barrier -> b128 LDS writes,
//       shfl-packed 16B stores + explicit drain before flag,
//     L1 issues h0[t] loads BEFORE its prog1 spin (latency hides in wait),
//     weights pinned in registers; pg padded [20]; G0 loads hoisted.

typedef unsigned short ush;
typedef short bf16x8 __attribute__((ext_vector_type(8)));
typedef float f32x4 __attribute__((ext_vector_type(4)));
typedef int i32x4 __attribute__((ext_vector_type(4)));
typedef unsigned long long u64;

#define TT 512
#define NA 64
#define NB 128
#define RING 8

__device__ __forceinline__ ush f2bf(float f) {
  __hip_bfloat16 h = __float2bfloat16(f);
  return *reinterpret_cast<ush*>(&h);
}
__device__ __forceinline__ float sigm(float x) { return 1.f / (1.f + __expf(-x)); }

__device__ __forceinline__ unsigned int aload(const unsigned int* p) {
  return __hip_atomic_load(p, __ATOMIC_RELAXED, __HIP_MEMORY_SCOPE_AGENT);
}
__device__ __forceinline__ void astore(unsigned int* p, unsigned int v) {
  __hip_atomic_store(p, v, __ATOMIC_RELAXED, __HIP_MEMORY_SCOPE_AGENT);
}

// ---------------------------------------------------------------------------
// Wb[j][k] = bf16(W[j][off+k]), 1024 cols (plain layout, for gemm128 B).
// ---------------------------------------------------------------------------
__global__ __launch_bounds__(256) void cast_w1k(const float* __restrict__ W,
                                                ush* __restrict__ Wb, int off) {
  int j = blockIdx.x;
  int k = threadIdx.x * 4;
  float4 v = *(const float4*)(W + (size_t)j * 2048 + off + k);
  ushort4 o;
  o.x = f2bf(v.x); o.y = f2bf(v.y); o.z = f2bf(v.z); o.w = f2bf(v.w);
  *(ushort4*)(Wb + (size_t)j * 1024 + k) = o;
}

// ---------------------------------------------------------------------------
// Pre-swizzle W0 h-half into per-(block,wave,chunk,lane) fragment order.
// ---------------------------------------------------------------------------
__global__ __launch_bounds__(256) void swz0(const float* __restrict__ W,
                                            ush* __restrict__ D) {
  int n = blockIdx.x * 256 + threadIdx.x;
  int lane = n & 63, ch = (n >> 6) & 15, w = (n >> 10) & 7, i = n >> 13;
  int l15 = lane & 15, quad = lane >> 4, g = w & 3, kh = w >> 2;
  int row = g * 1024 + i * 16 + l15;
  int col = 1024 + kh * 512 + ch * 32 + quad * 8;
  const float* src = W + (size_t)row * 2048 + col;
  float4 v0 = ((const float4*)src)[0];
  float4 v1 = ((const float4*)src)[1];
  ushort4 o0, o1;
  o0.x = f2bf(v0.x); o0.y = f2bf(v0.y); o0.z = f2bf(v0.z); o0.w = f2bf(v0.w);
  o1.x = f2bf(v1.x); o1.y = f2bf(v1.y); o1.z = f2bf(v1.z); o1.w = f2bf(v1.w);
  *(ushort4*)(D + (size_t)n * 8) = o0;
  *(ushort4*)(D + (size_t)n * 8 + 4) = o1;
}

// ---------------------------------------------------------------------------
// Pre-swizzle W1 (full K=2048). j=n>>13 (128 blocks).
// ---------------------------------------------------------------------------
__global__ __launch_bounds__(256) void swz1(const float* __restrict__ W,
                                            ush* __restrict__ D) {
  int n = blockIdx.x * 256 + threadIdx.x;
  int lane = n & 63, ch = (n >> 6) & 15, w = (n >> 10) & 7, j = n >> 13;
  int l15 = lane & 15, quad = lane >> 4, rh = w & 1, kq = w >> 1;
  int r32 = rh * 16 + l15;
  int row = (r32 >> 3) * 1024 + j * 8 + (r32 & 7);
  int col = kq * 512 + ch * 32 + quad * 8;
  const float* src = W + (size_t)row * 2048 + col;
  float4 v0 = ((const float4*)src)[0];
  float4 v1 = ((const float4*)src)[1];
  ushort4 o0, o1;
  o0.x = f2bf(v0.x); o0.y = f2bf(v0.y); o0.z = f2bf(v0.z); o0.w = f2bf(v0.w);
  o1.x = f2bf(v1.x); o1.y = f2bf(v1.y); o1.z = f2bf(v1.z); o1.w = f2bf(v1.w);
  *(ushort4*)(D + (size_t)n * 8) = o0;
  *(ushort4*)(D + (size_t)n * 8 + 4) = o1;
}

__global__ __launch_bounds__(256) void zeroreg(uint4* __restrict__ p) {
  p[blockIdx.x * 256 + threadIdx.x] = uint4{0, 0, 0, 0};
}

// ---------------------------------------------------------------------------
// 128x128 MFMA GEMM: G[r][j] = bias[j] + sum_k A[r][k]*Wb[j][k]. (unchanged)
// ---------------------------------------------------------------------------
__global__ __launch_bounds__(256) void gemm128(
    const float* __restrict__ xA, const ush* __restrict__ Wb,
    const float* __restrict__ bias, float* __restrict__ G, int t0) {
  __shared__ ush As[128][88];
  __shared__ ush Bs[128][88];
  int tid = threadIdx.x;
  int bn = blockIdx.x, bm = blockIdx.y;
  int srow = tid >> 1;
  int shalf = (tid & 1) * 32;
  int lane = tid & 63, quad = lane >> 4, l15 = lane & 15;
  int w = tid >> 6;
  int m_base = (w >> 1) * 64, n_base = (w & 1) * 64;

  int r = bm * 128 + srow;
  const float* axf = xA + ((size_t)(r & 31) * TT + t0 + (r >> 5)) * 1024;
  const ush* wrow = Wb + (size_t)(bn * 128 + srow) * 1024;

  f32x4 acc[4][4];
#pragma unroll
  for (int i = 0; i < 4; ++i)
#pragma unroll
    for (int j = 0; j < 4; ++j) acc[i][j] = f32x4{0.f, 0.f, 0.f, 0.f};

  for (int k0 = 0; k0 < 1024; k0 += 64) {
    {
      const float* p = axf + k0 + shalf;
      ush* d = &As[srow][shalf];
#pragma unroll
      for (int s = 0; s < 8; ++s) {
        float4 v = ((const float4*)p)[s];
        ushort4 o;
        o.x = f2bf(v.x); o.y = f2bf(v.y); o.z = f2bf(v.z); o.w = f2bf(v.w);
        ((ushort4*)d)[s] = o;
      }
    }
    {
      const uint4* p = (const uint4*)(wrow + k0 + shalf);
      uint4* d = (uint4*)&Bs[srow][shalf];
#pragma unroll
      for (int s = 0; s < 4; ++s) d[s] = p[s];
    }
    __syncthreads();
#pragma unroll
    for (int kc = 0; kc < 2; ++kc) {
      bf16x8 af[4], bf_[4];
#pragma unroll
      for (int i = 0; i < 4; ++i)
        af[i] = *(const bf16x8*)&As[m_base + i * 16 + l15][kc * 32 + quad * 8];
#pragma unroll
      for (int j = 0; j < 4; ++j)
        bf_[j] = *(const bf16x8*)&Bs[n_base + j * 16 + l15][kc * 32 + quad * 8];
#pragma unroll
      for (int i = 0; i < 4; ++i)
#pragma unroll
        for (int j = 0; j < 4; ++j)
          acc[i][j] = __builtin_amdgcn_mfma_f32_16x16x32_bf16(af[i], bf_[j],
                                                              acc[i][j], 0, 0, 0);
    }
    __syncthreads();
  }

#pragma unroll
  for (int j = 0; j < 4; ++j) {
    int col = bn * 128 + n_base + j * 16 + l15;
    float bj = bias[col];
#pragma unroll
    for (int i = 0; i < 4; ++i) {
      int row = bm * 128 + m_base + i * 16 + quad * 4;
#pragma unroll
      for (int reg = 0; reg < 4; ++reg)
        G[(size_t)(row + reg) * 4096 + col] = acc[i][j][reg] + bj;
    }
  }
}

// ---------------------------------------------------------------------------
// Persistent flag-synced recurrence for one chunk of Tc steps.
// 192 blocks x 512 thr, cooperative launch (co-residency only; no grid.sync).
// prog0[i*16] (64 L0 flags), prog1 at +1024 uints (128 L1 flags).
// ---------------------------------------------------------------------------
__global__ __launch_bounds__(512, 2) void lstm_persist(
    const float* __restrict__ G0, const ush* __restrict__ Wsw0,
    const ush* __restrict__ Wsw1, const float* __restrict__ b1,
    ush* __restrict__ h0r, ush* __restrict__ h1r,
    unsigned int* __restrict__ flg,
    float* __restrict__ cst, float* __restrict__ OUT,
    float* __restrict__ hno, float* __restrict__ cno,
    int t0, int Tc, int last) {
  __shared__ ush hbuf[65536];       // 128 KB (layer-0 uses first 64 KB)
  __shared__ float pg[8][32][20];   // padded partial-gate exchange
  char* hb = (char*)hbuf;

  int tid = threadIdx.x;
  int bid = blockIdx.x;
  int w = tid >> 6, lane = tid & 63, quad = lane >> 4, l15 = lane & 15;
  unsigned int* prog0 = flg;
  unsigned int* prog1 = flg + 1024;

  if (bid < NA) {
    // ================= layer-0 block: 16 cols x 4 gates, K=1024 ============
    int c0 = bid * 16;
    const ush* wp = Wsw0 + ((size_t)bid * 8 + w) * 8192 + (size_t)lane * 8;
    bf16x8 wreg[16];
#pragma unroll
    for (int ch = 0; ch < 16; ++ch) wreg[ch] = *(const bf16x8*)(wp + ch * 512);
#pragma unroll
    for (int ch = 0; ch < 16; ++ch) asm volatile("" : "+v"(wreg[ch]));
    int b = tid >> 4, c = tid & 15;
    int ci = b * 1024 + c0 + c;
    float creg = (t0 > 0) ? cst[ci] : 0.f;
    int m1c = t0;  // cached min(prog1) lower bound (wave0)
    int kbase = (w >> 2) * 1024 + quad * 16;
    int x0 = (l15 & 7) << 4;
    const char* a0p = hb + l15 * 2048;
    const char* a1p = hb + (16 + l15) * 2048;

    for (int s = 0; s < Tc; ++s) {
      int t = t0 + s;
      const float* grow = G0 + (size_t)(s * 32 + b) * 4096 + c0 + c;
      float g0v = grow[0], g1v = grow[1024], g2v = grow[2048], g3v = grow[3072];
      if (w == 0) {
        if ((int)aload(&prog0[lane * 16]) < t) {
          do { __builtin_amdgcn_s_sleep(1); } while ((int)aload(&prog0[lane * 16]) < t);
        }
        while (m1c < t - (RING - 1)) {  // ring-clobber guard (lazy)
          int m = (int)aload(&prog1[lane * 16]);
          m = min(m, (int)aload(&prog1[(64 + lane) * 16]));
#pragma unroll
          for (int d = 1; d < 64; d <<= 1) m = min(m, __shfl_xor(m, d));
          m1c = m;
          if (m1c < t - (RING - 1)) __builtin_amdgcn_s_sleep(2);
        }
      }
      __syncthreads();
      {  // stage h0[t-1]: 16B sc1 loads -> one waitcnt -> b128 LDS writes
        const char* src = (const char*)h0r + (size_t)((t - 1) & (RING - 1)) * 65536;
        i32x4 r_[8];
#pragma unroll
        for (int s2 = 0; s2 < 8; ++s2) {
          int gi = s2 * 512 + tid;
          asm volatile("global_load_dwordx4 %0, %1, off sc1"
                       : "=v"(r_[s2]) : "v"(src + (size_t)gi * 16));
        }
        asm volatile("s_waitcnt vmcnt(0)" ::: "memory");
        __builtin_amdgcn_sched_barrier(0);
#pragma unroll
        for (int s2 = 0; s2 < 8; ++s2) {
          int gi = s2 * 512 + tid;
          int r = gi >> 7, kb = (gi & 127) * 16;
          *(i32x4*)(hb + r * 2048 + (kb ^ ((r & 7) << 4))) = r_[s2];
        }
      }
      __syncthreads();
      f32x4 acc0 = {0.f, 0.f, 0.f, 0.f}, acc1 = {0.f, 0.f, 0.f, 0.f};
#pragma unroll
      for (int ch = 0; ch < 16; ++ch) {
        int kb = kbase + ch * 64;
        bf16x8 a0 = *(const bf16x8*)(a0p + (kb ^ x0));
        bf16x8 a1 = *(const bf16x8*)(a1p + (kb ^ x0));
        acc0 = __builtin_amdgcn_mfma_f32_16x16x32_bf16(a0, wreg[ch], acc0, 0, 0, 0);
        acc1 = __builtin_amdgcn_mfma_f32_16x16x32_bf16(a1, wreg[ch], acc1, 0, 0, 0);
      }
#pragma unroll
      for (int reg = 0; reg < 4; ++reg) {
        pg[w][quad * 4 + reg][l15] = acc0[reg];
        pg[w][16 + quad * 4 + reg][l15] = acc1[reg];
      }
      __syncthreads();
      float s0 = g0v + pg[0][b][c] + pg[4][b][c];
      float s1 = g1v + pg[1][b][c] + pg[5][b][c];
      float s2 = g2v + pg[2][b][c] + pg[6][b][c];
      float s3 = g3v + pg[3][b][c] + pg[7][b][c];
      float fg = sigm(s0), ig = sigm(s1), gv = tanhf(s2), og = sigm(s3);
      creg = fg * creg + ig * gv;
      float hnv = og * tanhf(creg);
      // pack 8 cols -> 16B sc1 store on (tid&7)==0 lanes
      float ho = __shfl_xor(hnv, 1);
      unsigned int pk = (unsigned int)f2bf(hnv) | ((unsigned int)f2bf(ho) << 16);
      unsigned int pk2 = __shfl_xor(pk, 2);
      u64 d0 = (u64)pk | ((u64)pk2 << 32);
      u64 d1 = (u64)__shfl_xor((long long)d0, 4);
      if ((tid & 7) == 0) {
        i32x4 v;
        v.x = (int)d0; v.y = (int)(d0 >> 32);
        v.z = (int)d1; v.w = (int)(d1 >> 32);
        char* dp = (char*)(h0r + (size_t)(t & (RING - 1)) * 32768 +
                           (size_t)b * 1024 + c0 + c);
        asm volatile("global_store_dwordx4 %0, %1, off sc1"
                     :: "v"(dp), "v"(v) : "memory");
      }
      if (t == TT - 1) hno[ci] = hnv;
      asm volatile("s_waitcnt vmcnt(0)" ::: "memory");
      __syncthreads();
      if (tid == 0) astore(&prog0[bid * 16], (unsigned int)(t + 1));
    }
    cst[ci] = creg;
    if (last) cno[ci] = creg;
  } else {
    // ============ layer-1 block: 8 cols x 4 gates, K=2048 (h0 ++ h1) =======
    int jb = bid - NA;
    int c0b = jb * 8;
    const ush* wp = Wsw1 + ((size_t)jb * 8 + w) * 8192 + (size_t)lane * 8;
    bf16x8 wreg[16];
#pragma unroll
    for (int ch = 0; ch < 16; ++ch) wreg[ch] = *(const bf16x8*)(wp + ch * 512);
#pragma unroll
    for (int ch = 0; ch < 16; ++ch) asm volatile("" : "+v"(wreg[ch]));
    bool pw = tid < 256;
    int b = tid >> 3, cc = tid & 7;
    int ci = b * 1024 + c0b + cc;  // meaningful only when pw
    float creg = 0.f;
    float biasr[4] = {0.f, 0.f, 0.f, 0.f};
    if (pw) {
      creg = (t0 > 0) ? cst[32768 + ci] : 0.f;
#pragma unroll
      for (int g = 0; g < 4; ++g) biasr[g] = b1[g * 1024 + c0b + cc];
    }
    int kq = w >> 1;
    int boff = (kq < 2) ? 0 : 65536;
    int kbase = (kq & 1) * 1024 + quad * 16;
    int x0 = (l15 & 7) << 4;
    const char* a0p = hb + boff + l15 * 2048;
    const char* a1p = a0p + 16 * 2048;

    for (int s = 0; s < Tc; ++s) {
      int t = t0 + s;
      if (w == 0) {  // h0[t] ready? (L0 runs ahead; usually satisfied)
        if ((int)aload(&prog0[lane * 16]) < t + 1) {
          do { __builtin_amdgcn_s_sleep(1); } while ((int)aload(&prog0[lane * 16]) < t + 1);
        }
      }
      __syncthreads();
      // issue h0[t] loads early (complete during the prog1 spin)
      i32x4 r0_[8];
      {
        const char* src = (const char*)h0r + (size_t)(t & (RING - 1)) * 65536;
#pragma unroll
        for (int s2 = 0; s2 < 8; ++s2) {
          int gi = s2 * 512 + tid;
          asm volatile("global_load_dwordx4 %0, %1, off sc1"
                       : "=v"(r0_[s2]) : "v"(src + (size_t)gi * 16));
        }
      }
      if (w == 0) {  // h1[t-1] ready: all 128 L1 blocks done step t-1
        while ((int)aload(&prog1[lane * 16]) < t ||
               (int)aload(&prog1[(64 + lane) * 16]) < t)
          __builtin_amdgcn_s_sleep(1);
      }
      __syncthreads();
      {  // issue h1[t-1] loads, wait all, write h0+h1 to LDS
        const char* src = (const char*)h1r + (size_t)((t - 1) & (RING - 1)) * 65536;
        i32x4 r1_[8];
#pragma unroll
        for (int s2 = 0; s2 < 8; ++s2) {
          int gi = s2 * 512 + tid;
          asm volatile("global_load_dwordx4 %0, %1, off sc1"
                       : "=v"(r1_[s2]) : "v"(src + (size_t)gi * 16));
        }
        asm volatile("s_waitcnt vmcnt(0)" ::: "memory");
        __builtin_amdgcn_sched_barrier(0);
#pragma unroll
        for (int s2 = 0; s2 < 8; ++s2) {
          int gi = s2 * 512 + tid;
          int r = gi >> 7, kb = (gi & 127) * 16;
          *(i32x4*)(hb + r * 2048 + (kb ^ ((r & 7) << 4))) = r0_[s2];
          *(i32x4*)(hb + 65536 + r * 2048 + (kb ^ ((r & 7) << 4))) = r1_[s2];
        }
      }
      __syncthreads();
      f32x4 acc0 = {0.f, 0.f, 0.f, 0.f}, acc1 = {0.f, 0.f, 0.f, 0.f};
#pragma unroll
      for (int ch = 0; ch < 16; ++ch) {
        int kb = kbase + ch * 64;
        bf16x8 a0 = *(const bf16x8*)(a0p + (kb ^ x0));
        bf16x8 a1 = *(const bf16x8*)(a1p + (kb ^ x0));
        acc0 = __builtin_amdgcn_mfma_f32_16x16x32_bf16(a0, wreg[ch], acc0, 0, 0, 0);
        acc1 = __builtin_amdgcn_mfma_f32_16x16x32_bf16(a1, wreg[ch], acc1, 0, 0, 0);
      }
#pragma unroll
      for (int reg = 0; reg < 4; ++reg) {
        pg[w][quad * 4 + reg][l15] = acc0[reg];
        pg[w][16 + quad * 4 + reg][l15] = acc1[reg];
      }
      __syncthreads();
      float hnv = 0.f;
      if (pw) {
        float sg[4];
#pragma unroll
        for (int g = 0; g < 4; ++g) {
          int r = g * 8 + cc, rrh = r >> 4, ri = r & 15;
          sg[g] = biasr[g] + pg[rrh][b][ri] + pg[2 + rrh][b][ri] +
                  pg[4 + rrh][b][ri] + pg[6 + rrh][b][ri];
        }
        float fg = sigm(sg[0]), ig = sigm(sg[1]), gv = tanhf(sg[2]),
              og = sigm(sg[3]);
        creg = fg * creg + ig * gv;
        hnv = og * tanhf(creg);
        // pack 8 cols -> one 16B sc1 store per b-row (cc==0 lanes)
        float ho = __shfl_xor(hnv, 1);
        unsigned int pk = (unsigned int)f2bf(hnv) | ((unsigned int)f2bf(ho) << 16);
        unsigned int pk2 = __shfl_xor(pk, 2);
        u64 d0 = (u64)pk | ((u64)pk2 << 32);
        u64 d1 = (u64)__shfl_xor((long long)d0, 4);
        if ((tid & 7) == 0) {
          i32x4 v;
          v.x = (int)d0; v.y = (int)(d0 >> 32);
          v.z = (int)d1; v.w = (int)(d1 >> 32);
          char* dp = (char*)(h1r + (size_t)(t & (RING - 1)) * 32768 +
                             (size_t)b * 1024 + c0b);
          asm volatile("global_store_dwordx4 %0, %1, off sc1"
                       :: "v"(dp), "v"(v) : "memory");
        }
      }
      asm volatile("s_waitcnt vmcnt(0)" ::: "memory");
      __syncthreads();
      if (tid == 0) astore(&prog1[jb * 16], (unsigned int)(t + 1));
      if (pw) {  // OUT/h_n off the critical path
        OUT[((size_t)b * TT + t) * 1024 + c0b + cc] = hnv;
        if (t == TT - 1) hno[32768 + ci] = hnv;
      }
    }
    if (pw) {
      cst[32768 + ci] = creg;
      if (last) cno[32768 + ci] = creg;
    }
  }
}

extern "C" void kernel_launch(void* const* d_in, const int* in_sizes, int n_in,
                              void* d_out, int out_size, void* d_ws, size_t ws_size,
                              hipStream_t stream) {
  const float* x = (const float*)d_in[0];
  const float* W0 = (const float*)d_in[1];
  const float* b0 = (const float*)d_in[2];
  const float* W1 = (const float*)d_in[3];
  const float* b1 = (const float*)d_in[4];
  float* OUT = (float*)d_out;

  // ws layout (bytes):
  //   Wxb0 [4096][1024] bf16 : 0        (gemm B, x-half of W0)
  //   Wsw0 swizzled 8 MB     : 8388608
  //   Wsw1 swizzled 16 MB    : 16777216
  //   h0r  RINGx64KB         : 33554432
  //   h1r  RINGx64KB         : 34078720
  //   flg  16 KB             : 34603008  (prog0/prog1 per-block flags)
  //   cst  [2][32][1024] f32 : 34619392
  //   G0   [Tc*32][4096] f32 : 34881536
  int Tc = 4;
  {
    const int cand[8] = {512, 256, 128, 64, 32, 16, 8, 4};
    for (int i = 0; i < 8; ++i) {
      size_t need = 34881536ull + (size_t)cand[i] * 524288;
      if (need <= ws_size) { Tc = cand[i]; break; }
    }
  }
  char* ws = (char*)d_ws;
  ush* Wxb0 = (ush*)ws;
  ush* Wsw0 = (ush*)(ws + 8388608);
  ush* Wsw1 = (ush*)(ws + 16777216);
  ush* h0r = (ush*)(ws + 33554432);
  ush* h1r = (ush*)(ws + 34078720);
  unsigned int* flg = (unsigned int*)(ws + 34603008);
  float* cst = (float*)(ws + 34619392);
  float* G = (float*)(ws + 34881536);

  cast_w1k<<<4096, 256, 0, stream>>>(W0, Wxb0, 0);
  swz0<<<2048, 256, 0, stream>>>(W0, Wsw0);
  swz1<<<4096, 256, 0, stream>>>(W1, Wsw1);
  zeroreg<<<260, 256, 0, stream>>>((uint4*)(ws + 33554432));  // rings + flags

  float* hnp = OUT + 16777216;
  float* cnp = OUT + 16777216 + 65536;
  dim3 ggrid(32, (unsigned)(Tc * 32 / 128));

  const int NCH = TT / Tc;
  for (int ch = 0; ch < NCH; ++ch) {
    int t0v = ch * Tc;
    int lastv = (ch == NCH - 1) ? 1 : 0;
    gemm128<<<ggrid, 256, 0, stream>>>(x, Wxb0, b0, G, t0v);
    void* pargs[14] = {(void*)&G,    (void*)&Wsw0, (void*)&Wsw1, (void*)&b1,
                       (void*)&h0r,  (void*)&h1r,  (void*)&flg,  (void*)&cst,
                       (void*)&OUT,  (void*)&hnp,  (void*)&cnp,  (void*)&t0v,
                       (void*)&Tc,   (void*)&lastv};
    hipLaunchCooperativeKernel((void*)lstm_persist, dim3(NA + NB), dim3(512),
                               pargs, 0, stream);
  }
}

// Round 9
// 2683.409 us; speedup vs baseline: 2.0322x; 1.0720x over previous
//
#include <hip/hip_runtime.h>
#include <hip/hip_bf16.h>
#include <cstdint>
#include <cstddef>

// B=32, T=512, I=H=1024, L=2, gates 4H=4096. fp32 in/out.
// d_out fp32: outputs[32][512][1024] ++ h_n[2][32][1024] ++ c_n[2][32][1024].
// Per chunk of Tc steps:
//   gemm128: G0 = x@Wx0^T + b0 (bf16 MFMA, fp32 out; Wx0 pre-cast bf16)
//   lstm_persist (cooperative, 256 blocks, flag-sync, no grid.sync):
//     blocks   0..63 : L0 recurrence (16 cols x 4 gates, K=1024)
//     blocks  64..127: P-blocks: P[t] = W1h0 . h0[t], pipelined ~8 ahead
//     blocks 128..255: L1 critical loop: ONLY h1 staging + K=1024 MFMA;
//                      h0 contribution arrives as precomputed P (early,
//                      off-critical), gates = bias + P + own partials.
//     16B sc1 ring transfers, per-block flags, weights pinned in regs.

typedef unsigned short ush;
typedef short bf16x8 __attribute__((ext_vector_type(8)));
typedef float f32x4 __attribute__((ext_vector_type(4)));
typedef int i32x4 __attribute__((ext_vector_type(4)));
typedef unsigned long long u64;

#define TT 512
#define NA 64
#define RING 8

__device__ __forceinline__ ush f2bf(float f) {
  __hip_bfloat16 h = __float2bfloat16(f);
  return *reinterpret_cast<ush*>(&h);
}
__device__ __forceinline__ float sigm(float x) { return 1.f / (1.f + __expf(-x)); }

__device__ __forceinline__ unsigned int aload(const unsigned int* p) {
  return __hip_atomic_load(p, __ATOMIC_RELAXED, __HIP_MEMORY_SCOPE_AGENT);
}
__device__ __forceinline__ void astore(unsigned int* p, unsigned int v) {
  __hip_atomic_store(p, v, __ATOMIC_RELAXED, __HIP_MEMORY_SCOPE_AGENT);
}
__device__ __forceinline__ float afload(const float* p) {
  return __hip_atomic_load(p, __ATOMIC_RELAXED, __HIP_MEMORY_SCOPE_AGENT);
}

// ---------------------------------------------------------------------------
// Wb[j][k] = bf16(W[j][off+k]), 1024 cols (plain layout, for gemm128 B).
// ---------------------------------------------------------------------------
__global__ __launch_bounds__(256) void cast_w1k(const float* __restrict__ W,
                                                ush* __restrict__ Wb, int off) {
  int j = blockIdx.x;
  int k = threadIdx.x * 4;
  float4 v = *(const float4*)(W + (size_t)j * 2048 + off + k);
  ushort4 o;
  o.x = f2bf(v.x); o.y = f2bf(v.y); o.z = f2bf(v.z); o.w = f2bf(v.w);
  *(ushort4*)(Wb + (size_t)j * 1024 + k) = o;
}

// ---------------------------------------------------------------------------
// L0-style pre-swizzle: 64 blocks x 16 cols x 4 gates, K=1024 at col coloff.
// n < 524288. lane=n&63, ch=(n>>6)&15, w=(n>>10)&7, i=n>>13.
// ---------------------------------------------------------------------------
__global__ __launch_bounds__(256) void swzW(const float* __restrict__ W,
                                            ush* __restrict__ D, int coloff) {
  int n = blockIdx.x * 256 + threadIdx.x;
  int lane = n & 63, ch = (n >> 6) & 15, w = (n >> 10) & 7, i = n >> 13;
  int l15 = lane & 15, quad = lane >> 4, g = w & 3, kh = w >> 2;
  int row = g * 1024 + i * 16 + l15;
  int col = coloff + kh * 512 + ch * 32 + quad * 8;
  const float* src = W + (size_t)row * 2048 + col;
  float4 v0 = ((const float4*)src)[0];
  float4 v1 = ((const float4*)src)[1];
  ushort4 o0, o1;
  o0.x = f2bf(v0.x); o0.y = f2bf(v0.y); o0.z = f2bf(v0.z); o0.w = f2bf(v0.w);
  o1.x = f2bf(v1.x); o1.y = f2bf(v1.y); o1.z = f2bf(v1.z); o1.w = f2bf(v1.w);
  *(ushort4*)(D + (size_t)n * 8) = o0;
  *(ushort4*)(D + (size_t)n * 8 + 4) = o1;
}

// ---------------------------------------------------------------------------
// W1 h1-half pre-swizzle for L1 blocks: 128 blocks x 8 cols, K=1024 (col 1024+).
// n < 524288. lane=n&63, ch=(n>>6)&7, w=(n>>9)&7, jb=n>>12. rh=w&1, kq=w>>1.
// ---------------------------------------------------------------------------
__global__ __launch_bounds__(256) void swz1h(const float* __restrict__ W,
                                             ush* __restrict__ D) {
  int n = blockIdx.x * 256 + threadIdx.x;
  int lane = n & 63, ch = (n >> 6) & 7, w = (n >> 9) & 7, jb = n >> 12;
  int l15 = lane & 15, quad = lane >> 4, rh = w & 1, kq = w >> 1;
  int r32 = rh * 16 + l15;
  int row = (r32 >> 3) * 1024 + jb * 8 + (r32 & 7);
  int col = 1024 + kq * 256 + ch * 32 + quad * 8;
  const float* src = W + (size_t)row * 2048 + col;
  float4 v0 = ((const float4*)src)[0];
  float4 v1 = ((const float4*)src)[1];
  ushort4 o0, o1;
  o0.x = f2bf(v0.x); o0.y = f2bf(v0.y); o0.z = f2bf(v0.z); o0.w = f2bf(v0.w);
  o1.x = f2bf(v1.x); o1.y = f2bf(v1.y); o1.z = f2bf(v1.z); o1.w = f2bf(v1.w);
  *(ushort4*)(D + (size_t)n * 8) = o0;
  *(ushort4*)(D + (size_t)n * 8 + 4) = o1;
}

__global__ __launch_bounds__(256) void zeroreg(uint4* __restrict__ p) {
  p[blockIdx.x * 256 + threadIdx.x] = uint4{0, 0, 0, 0};
}

// ---------------------------------------------------------------------------
// 128x128 MFMA GEMM: G[r][j] = bias[j] + sum_k A[r][k]*Wb[j][k]. (unchanged)
// ---------------------------------------------------------------------------
__global__ __launch_bounds__(256) void gemm128(
    const float* __restrict__ xA, const ush* __restrict__ Wb,
    const float* __restrict__ bias, float* __restrict__ G, int t0) {
  __shared__ ush As[128][88];
  __shared__ ush Bs[128][88];
  int tid = threadIdx.x;
  int bn = blockIdx.x, bm = blockIdx.y;
  int srow = tid >> 1;
  int shalf = (tid & 1) * 32;
  int lane = tid & 63, quad = lane >> 4, l15 = lane & 15;
  int w = tid >> 6;
  int m_base = (w >> 1) * 64, n_base = (w & 1) * 64;

  int r = bm * 128 + srow;
  const float* axf = xA + ((size_t)(r & 31) * TT + t0 + (r >> 5)) * 1024;
  const ush* wrow = Wb + (size_t)(bn * 128 + srow) * 1024;

  f32x4 acc[4][4];
#pragma unroll
  for (int i = 0; i < 4; ++i)
#pragma unroll
    for (int j = 0; j < 4; ++j) acc[i][j] = f32x4{0.f, 0.f, 0.f, 0.f};

  for (int k0 = 0; k0 < 1024; k0 += 64) {
    {
      const float* p = axf + k0 + shalf;
      ush* d = &As[srow][shalf];
#pragma unroll
      for (int s = 0; s < 8; ++s) {
        float4 v = ((const float4*)p)[s];
        ushort4 o;
        o.x = f2bf(v.x); o.y = f2bf(v.y); o.z = f2bf(v.z); o.w = f2bf(v.w);
        ((ushort4*)d)[s] = o;
      }
    }
    {
      const uint4* p = (const uint4*)(wrow + k0 + shalf);
      uint4* d = (uint4*)&Bs[srow][shalf];
#pragma unroll
      for (int s = 0; s < 4; ++s) d[s] = p[s];
    }
    __syncthreads();
#pragma unroll
    for (int kc = 0; kc < 2; ++kc) {
      bf16x8 af[4], bf_[4];
#pragma unroll
      for (int i = 0; i < 4; ++i)
        af[i] = *(const bf16x8*)&As[m_base + i * 16 + l15][kc * 32 + quad * 8];
#pragma unroll
      for (int j = 0; j < 4; ++j)
        bf_[j] = *(const bf16x8*)&Bs[n_base + j * 16 + l15][kc * 32 + quad * 8];
#pragma unroll
      for (int i = 0; i < 4; ++i)
#pragma unroll
        for (int j = 0; j < 4; ++j)
          acc[i][j] = __builtin_amdgcn_mfma_f32_16x16x32_bf16(af[i], bf_[j],
                                                              acc[i][j], 0, 0, 0);
    }
    __syncthreads();
  }

#pragma unroll
  for (int j = 0; j < 4; ++j) {
    int col = bn * 128 + n_base + j * 16 + l15;
    float bj = bias[col];
#pragma unroll
    for (int i = 0; i < 4; ++i) {
      int row = bm * 128 + m_base + i * 16 + quad * 4;
#pragma unroll
      for (int reg = 0; reg < 4; ++reg)
        G[(size_t)(row + reg) * 4096 + col] = acc[i][j][reg] + bj;
    }
  }
}

// ---------------------------------------------------------------------------
// Persistent flag-synced recurrence for one chunk of Tc steps.
// 256 blocks x 512 thr. flags: prog0 @ flg, prog1 @ flg+1024, progP @ flg+3072.
// ---------------------------------------------------------------------------
__global__ __launch_bounds__(512, 2) void lstm_persist(
    const float* __restrict__ G0, const ush* __restrict__ Wsw0,
    const ush* __restrict__ WswP, const ush* __restrict__ Wsw1h,
    const float* __restrict__ b1,
    ush* __restrict__ h0r, ush* __restrict__ h1r, float* __restrict__ Pr,
    unsigned int* __restrict__ flg,
    float* __restrict__ cst, float* __restrict__ OUT,
    float* __restrict__ hno, float* __restrict__ cno,
    int t0, int Tc, int last) {
  __shared__ ush hbuf[32768];       // 64 KB h staging
  __shared__ float pg[8][32][20];   // padded partial-gate exchange
  char* hb = (char*)hbuf;

  int tid = threadIdx.x;
  int bid = blockIdx.x;
  int w = tid >> 6, lane = tid & 63, quad = lane >> 4, l15 = lane & 15;
  unsigned int* prog0 = flg;
  unsigned int* prog1 = flg + 1024;
  unsigned int* progP = flg + 3072;

  if (bid < NA) {
    // ================= layer-0 block: 16 cols x 4 gates, K=1024 ============
    int c0 = bid * 16;
    const ush* wp = Wsw0 + ((size_t)bid * 8 + w) * 8192 + (size_t)lane * 8;
    bf16x8 wreg[16];
#pragma unroll
    for (int ch = 0; ch < 16; ++ch) wreg[ch] = *(const bf16x8*)(wp + ch * 512);
#pragma unroll
    for (int ch = 0; ch < 16; ++ch) asm volatile("" : "+v"(wreg[ch]));
    int b = tid >> 4, c = tid & 15;
    int ci = b * 1024 + c0 + c;
    float creg = (t0 > 0) ? cst[ci] : 0.f;
    int mPc = t0;  // cached min(progP) lower bound (wave0)
    int kbase = (w >> 2) * 1024 + quad * 16;
    int x0 = (l15 & 7) << 4;
    const char* a0p = hb + l15 * 2048;
    const char* a1p = hb + (16 + l15) * 2048;

    for (int s = 0; s < Tc; ++s) {
      int t = t0 + s;
      const float* grow = G0 + (size_t)(s * 32 + b) * 4096 + c0 + c;
      float g0v = grow[0], g1v = grow[1024], g2v = grow[2048], g3v = grow[3072];
      if (w == 0) {
        if ((int)aload(&prog0[lane * 16]) < t) {
          do { __builtin_amdgcn_s_sleep(1); } while ((int)aload(&prog0[lane * 16]) < t);
        }
        while (mPc < t - (RING - 1)) {  // h0r clobber guard: P consumers
          int m = (int)aload(&progP[lane * 16]);
#pragma unroll
          for (int d = 1; d < 64; d <<= 1) m = min(m, __shfl_xor(m, d));
          mPc = m;
          if (mPc < t - (RING - 1)) __builtin_amdgcn_s_sleep(2);
        }
      }
      __syncthreads();
      {  // stage h0[t-1]: 16B sc1 loads -> one waitcnt -> b128 LDS writes
        const char* src = (const char*)h0r + (size_t)((t - 1) & (RING - 1)) * 65536;
        i32x4 r_[8];
#pragma unroll
        for (int s2 = 0; s2 < 8; ++s2) {
          int gi = s2 * 512 + tid;
          asm volatile("global_load_dwordx4 %0, %1, off sc1"
                       : "=v"(r_[s2]) : "v"(src + (size_t)gi * 16));
        }
        asm volatile("s_waitcnt vmcnt(0)" ::: "memory");
        __builtin_amdgcn_sched_barrier(0);
#pragma unroll
        for (int s2 = 0; s2 < 8; ++s2) {
          int gi = s2 * 512 + tid;
          int r = gi >> 7, kb = (gi & 127) * 16;
          *(i32x4*)(hb + r * 2048 + (kb ^ ((r & 7) << 4))) = r_[s2];
        }
      }
      __syncthreads();
      f32x4 acc0 = {0.f, 0.f, 0.f, 0.f}, acc1 = {0.f, 0.f, 0.f, 0.f};
#pragma unroll
      for (int ch = 0; ch < 16; ++ch) {
        int kb = kbase + ch * 64;
        bf16x8 a0 = *(const bf16x8*)(a0p + (kb ^ x0));
        bf16x8 a1 = *(const bf16x8*)(a1p + (kb ^ x0));
        acc0 = __builtin_amdgcn_mfma_f32_16x16x32_bf16(a0, wreg[ch], acc0, 0, 0, 0);
        acc1 = __builtin_amdgcn_mfma_f32_16x16x32_bf16(a1, wreg[ch], acc1, 0, 0, 0);
      }
#pragma unroll
      for (int reg = 0; reg < 4; ++reg) {
        pg[w][quad * 4 + reg][l15] = acc0[reg];
        pg[w][16 + quad * 4 + reg][l15] = acc1[reg];
      }
      __syncthreads();
      float s0 = g0v + pg[0][b][c] + pg[4][b][c];
      float s1 = g1v + pg[1][b][c] + pg[5][b][c];
      float s2 = g2v + pg[2][b][c] + pg[6][b][c];
      float s3 = g3v + pg[3][b][c] + pg[7][b][c];
      float fg = sigm(s0), ig = sigm(s1), gv = tanhf(s2), og = sigm(s3);
      creg = fg * creg + ig * gv;
      float hnv = og * tanhf(creg);
      float ho = __shfl_xor(hnv, 1);
      unsigned int pk = (unsigned int)f2bf(hnv) | ((unsigned int)f2bf(ho) << 16);
      unsigned int pk2 = __shfl_xor(pk, 2);
      u64 d0 = (u64)pk | ((u64)pk2 << 32);
      u64 d1 = (u64)__shfl_xor((long long)d0, 4);
      if ((tid & 7) == 0) {
        i32x4 v;
        v.x = (int)d0; v.y = (int)(d0 >> 32);
        v.z = (int)d1; v.w = (int)(d1 >> 32);
        char* dp = (char*)(h0r + (size_t)(t & (RING - 1)) * 32768 +
                           (size_t)b * 1024 + c0 + c);
        asm volatile("global_store_dwordx4 %0, %1, off sc1"
                     :: "v"(dp), "v"(v) : "memory");
      }
      if (t == TT - 1) hno[ci] = hnv;
      asm volatile("s_waitcnt vmcnt(0)" ::: "memory");
      __syncthreads();
      if (tid == 0) astore(&prog0[bid * 16], (unsigned int)(t + 1));
    }
    cst[ci] = creg;
    if (last) cno[ci] = creg;
  } else if (bid < 2 * NA) {
    // ======== P-block: P[t] = W1h0 . h0[t], 16 cols x 4 gates, K=1024 ======
    int p = bid - NA;
    int c0 = p * 16;
    const ush* wp = WswP + ((size_t)p * 8 + w) * 8192 + (size_t)lane * 8;
    bf16x8 wreg[16];
#pragma unroll
    for (int ch = 0; ch < 16; ++ch) wreg[ch] = *(const bf16x8*)(wp + ch * 512);
#pragma unroll
    for (int ch = 0; ch < 16; ++ch) asm volatile("" : "+v"(wreg[ch]));
    int b = tid >> 4, c = tid & 15;
    int m1c = t0;  // cached min(prog1) lower bound (Pr clobber guard)
    int kbase = (w >> 2) * 1024 + quad * 16;
    int x0 = (l15 & 7) << 4;
    const char* a0p = hb + l15 * 2048;
    const char* a1p = hb + (16 + l15) * 2048;

    for (int s = 0; s < Tc; ++s) {
      int t = t0 + s;
      if (w == 0) {
        if ((int)aload(&prog0[lane * 16]) < t + 1) {  // h0[t] ready
          do { __builtin_amdgcn_s_sleep(1); } while ((int)aload(&prog0[lane * 16]) < t + 1);
        }
        while (m1c < t - (RING - 1)) {  // Pr slot guard: L1 consumed t-8
          int m = (int)aload(&prog1[lane * 16]);
          m = min(m, (int)aload(&prog1[(64 + lane) * 16]));
#pragma unroll
          for (int d = 1; d < 64; d <<= 1) m = min(m, __shfl_xor(m, d));
          m1c = m;
          if (m1c < t - (RING - 1)) __builtin_amdgcn_s_sleep(2);
        }
      }
      __syncthreads();
      {  // stage h0[t]
        const char* src = (const char*)h0r + (size_t)(t & (RING - 1)) * 65536;
        i32x4 r_[8];
#pragma unroll
        for (int s2 = 0; s2 < 8; ++s2) {
          int gi = s2 * 512 + tid;
          asm volatile("global_load_dwordx4 %0, %1, off sc1"
                       : "=v"(r_[s2]) : "v"(src + (size_t)gi * 16));
        }
        asm volatile("s_waitcnt vmcnt(0)" ::: "memory");
        __builtin_amdgcn_sched_barrier(0);
#pragma unroll
        for (int s2 = 0; s2 < 8; ++s2) {
          int gi = s2 * 512 + tid;
          int r = gi >> 7, kb = (gi & 127) * 16;
          *(i32x4*)(hb + r * 2048 + (kb ^ ((r & 7) << 4))) = r_[s2];
        }
      }
      __syncthreads();
      f32x4 acc0 = {0.f, 0.f, 0.f, 0.f}, acc1 = {0.f, 0.f, 0.f, 0.f};
#pragma unroll
      for (int ch = 0; ch < 16; ++ch) {
        int kb = kbase + ch * 64;
        bf16x8 a0 = *(const bf16x8*)(a0p + (kb ^ x0));
        bf16x8 a1 = *(const bf16x8*)(a1p + (kb ^ x0));
        acc0 = __builtin_amdgcn_mfma_f32_16x16x32_bf16(a0, wreg[ch], acc0, 0, 0, 0);
        acc1 = __builtin_amdgcn_mfma_f32_16x16x32_bf16(a1, wreg[ch], acc1, 0, 0, 0);
      }
#pragma unroll
      for (int reg = 0; reg < 4; ++reg) {
        pg[w][quad * 4 + reg][l15] = acc0[reg];
        pg[w][16 + quad * 4 + reg][l15] = acc1[reg];
      }
      __syncthreads();
      float s0 = pg[0][b][c] + pg[4][b][c];
      float s1 = pg[1][b][c] + pg[5][b][c];
      float s2 = pg[2][b][c] + pg[6][b][c];
      float s3 = pg[3][b][c] + pg[7][b][c];
      {
        i32x4 v;
        v.x = __float_as_int(s0); v.y = __float_as_int(s1);
        v.z = __float_as_int(s2); v.w = __float_as_int(s3);
        char* dp = (char*)Pr + (size_t)(t & (RING - 1)) * 524288 +
                   (size_t)(b * 1024 + c0 + c) * 16;
        asm volatile("global_store_dwordx4 %0, %1, off sc1"
                     :: "v"(dp), "v"(v) : "memory");
      }
      asm volatile("s_waitcnt vmcnt(0)" ::: "memory");
      __syncthreads();
      if (tid == 0) astore(&progP[p * 16], (unsigned int)(t + 1));
    }
  } else {
    // ====== layer-1 block: 8 cols x 4 gates, CRITICAL K=1024 (h1 only) =====
    int jb = bid - 2 * NA;
    int c0b = jb * 8;
    const ush* wp = Wsw1h + ((size_t)jb * 8 + w) * 4096 + (size_t)lane * 8;
    bf16x8 wreg[8];
#pragma unroll
    for (int ch = 0; ch < 8; ++ch) wreg[ch] = *(const bf16x8*)(wp + ch * 512);
#pragma unroll
    for (int ch = 0; ch < 8; ++ch) asm volatile("" : "+v"(wreg[ch]));
    bool pw = tid < 256;
    int b = tid >> 3, cc = tid & 7;
    int ci = b * 1024 + c0b + cc;  // meaningful only when pw
    float creg = 0.f;
    float biasr[4] = {0.f, 0.f, 0.f, 0.f};
    if (pw) {
      creg = (t0 > 0) ? cst[32768 + ci] : 0.f;
#pragma unroll
      for (int g = 0; g < 4; ++g) biasr[g] = b1[g * 1024 + c0b + cc];
    }
    int kq = w >> 1;
    int kbase = kq * 512 + quad * 16;
    int x0 = (l15 & 7) << 4;
    const char* a0p = hb + l15 * 2048;
    const char* a1p = hb + (16 + l15) * 2048;

    for (int s = 0; s < Tc; ++s) {
      int t = t0 + s;
      if (w == 0) {  // P[t] ready? (P runs ~8 ahead; usually satisfied)
        if ((int)aload(&progP[(jb >> 1) * 16]) < t + 1) {
          do { __builtin_amdgcn_s_sleep(1); } while ((int)aload(&progP[(jb >> 1) * 16]) < t + 1);
        }
      }
      __syncthreads();
      float pf[4] = {0.f, 0.f, 0.f, 0.f};
      if (pw) {  // early-issue P loads (off critical path; waitcnt at use)
        const float* pp = (const float*)((const char*)Pr +
                          (size_t)(t & (RING - 1)) * 524288) +
                          (size_t)(b * 1024 + c0b + cc) * 4;
#pragma unroll
        for (int g = 0; g < 4; ++g) pf[g] = afload(pp + g);
      }
      if (w == 0) {  // h1[t-1] ready: all 128 L1 blocks done step t-1
        while ((int)aload(&prog1[lane * 16]) < t ||
               (int)aload(&prog1[(64 + lane) * 16]) < t)
          __builtin_amdgcn_s_sleep(1);
      }
      __syncthreads();
      {  // stage h1[t-1] (the only critical staging: 64 KB)
        const char* src = (const char*)h1r + (size_t)((t - 1) & (RING - 1)) * 65536;
        i32x4 r1_[8];
#pragma unroll
        for (int s2 = 0; s2 < 8; ++s2) {
          int gi = s2 * 512 + tid;
          asm volatile("global_load_dwordx4 %0, %1, off sc1"
                       : "=v"(r1_[s2]) : "v"(src + (size_t)gi * 16));
        }
        asm volatile("s_waitcnt vmcnt(0)" ::: "memory");
        __builtin_amdgcn_sched_barrier(0);
#pragma unroll
        for (int s2 = 0; s2 < 8; ++s2) {
          int gi = s2 * 512 + tid;
          int r = gi >> 7, kb = (gi & 127) * 16;
          *(i32x4*)(hb + r * 2048 + (kb ^ ((r & 7) << 4))) = r1_[s2];
        }
      }
      __syncthreads();
      f32x4 acc0 = {0.f, 0.f, 0.f, 0.f}, acc1 = {0.f, 0.f, 0.f, 0.f};
#pragma unroll
      for (int ch = 0; ch < 8; ++ch) {
        int kb = kbase + ch * 64;
        bf16x8 a0 = *(const bf16x8*)(a0p + (kb ^ x0));
        bf16x8 a1 = *(const bf16x8*)(a1p + (kb ^ x0));
        acc0 = __builtin_amdgcn_mfma_f32_16x16x32_bf16(a0, wreg[ch], acc0, 0, 0, 0);
        acc1 = __builtin_amdgcn_mfma_f32_16x16x32_bf16(a1, wreg[ch], acc1, 0, 0, 0);
      }
#pragma unroll
      for (int reg = 0; reg < 4; ++reg) {
        pg[w][quad * 4 + reg][l15] = acc0[reg];
        pg[w][16 + quad * 4 + reg][l15] = acc1[reg];
      }
      __syncthreads();
      float hnv = 0.f;
      if (pw) {
        float sg[4];
#pragma unroll
        for (int g = 0; g < 4; ++g) {
          int r = g * 8 + cc, rrh = r >> 4, ri = r & 15;
          sg[g] = biasr[g] + pf[g] + pg[rrh][b][ri] + pg[2 + rrh][b][ri] +
                  pg[4 + rrh][b][ri] + pg[6 + rrh][b][ri];
        }
        float fg = sigm(sg[0]), ig = sigm(sg[1]), gv = tanhf(sg[2]),
              og = sigm(sg[3]);
        creg = fg * creg + ig * gv;
        hnv = og * tanhf(creg);
        float ho = __shfl_xor(hnv, 1);
        unsigned int pk = (unsigned int)f2bf(hnv) | ((unsigned int)f2bf(ho) << 16);
        unsigned int pk2 = __shfl_xor(pk, 2);
        u64 d0 = (u64)pk | ((u64)pk2 << 32);
        u64 d1 = (u64)__shfl_xor((long long)d0, 4);
        if ((tid & 7) == 0) {
          i32x4 v;
          v.x = (int)d0; v.y = (int)(d0 >> 32);
          v.z = (int)d1; v.w = (int)(d1 >> 32);
          char* dp = (char*)(h1r + (size_t)(t & (RING - 1)) * 32768 +
                             (size_t)b * 1024 + c0b);
          asm volatile("global_store_dwordx4 %0, %1, off sc1"
                       :: "v"(dp), "v"(v) : "memory");
        }
      }
      asm volatile("s_waitcnt vmcnt(0)" ::: "memory");
      __syncthreads();
      if (tid == 0) astore(&prog1[jb * 16], (unsigned int)(t + 1));
      if (pw) {  // OUT/h_n off the critical path
        OUT[((size_t)b * TT + t) * 1024 + c0b + cc] = hnv;
        if (t == TT - 1) hno[32768 + ci] = hnv;
      }
    }
    if (pw) {
      cst[32768 + ci] = creg;
      if (last) cno[32768 + ci] = creg;
    }
  }
}

extern "C" void kernel_launch(void* const* d_in, const int* in_sizes, int n_in,
                              void* d_out, int out_size, void* d_ws, size_t ws_size,
                              hipStream_t stream) {
  const float* x = (const float*)d_in[0];
  const float* W0 = (const float*)d_in[1];
  const float* b0 = (const float*)d_in[2];
  const float* W1 = (const float*)d_in[3];
  const float* b1 = (const float*)d_in[4];
  float* OUT = (float*)d_out;

  // ws layout (bytes):
  //   Wxb0  [4096][1024] bf16 : 0         (gemm B, x-half of W0)
  //   Wsw0  swizzled 8 MB     : 8388608   (W0 h-half, L0 blocks)
  //   WswP  swizzled 8 MB     : 16777216  (W1 h0-half, P blocks)
  //   Wsw1h swizzled 8 MB     : 25165824  (W1 h1-half, L1 blocks)
  //   h0r   RINGx64KB         : 33554432
  //   h1r   RINGx64KB         : 34078720
  //   Pr    RINGx512KB f32    : 34603008
  //   flg   16 KB             : 38797312
  //   cst   [2][32][1024] f32 : 38813696
  //   G0    [Tc*32][4096] f32 : 39075840
  int Tc = 4;
  {
    const int cand[8] = {512, 256, 128, 64, 32, 16, 8, 4};
    for (int i = 0; i < 8; ++i) {
      size_t need = 39075840ull + (size_t)cand[i] * 524288;
      if (need <= ws_size) { Tc = cand[i]; break; }
    }
  }
  char* ws = (char*)d_ws;
  ush* Wxb0 = (ush*)ws;
  ush* Wsw0 = (ush*)(ws + 8388608);
  ush* WswP = (ush*)(ws + 16777216);
  ush* Wsw1h = (ush*)(ws + 25165824);
  ush* h0r = (ush*)(ws + 33554432);
  ush* h1r = (ush*)(ws + 34078720);
  float* Pr = (float*)(ws + 34603008);
  unsigned int* flg = (unsigned int*)(ws + 38797312);
  float* cst = (float*)(ws + 38813696);
  float* G = (float*)(ws + 39075840);

  cast_w1k<<<4096, 256, 0, stream>>>(W0, Wxb0, 0);
  swzW<<<2048, 256, 0, stream>>>(W0, Wsw0, 1024);
  swzW<<<2048, 256, 0, stream>>>(W1, WswP, 0);
  swz1h<<<2048, 256, 0, stream>>>(W1, Wsw1h);
  // zero rings + Pr + flags: [33554432, 38813696) = 5259264 B = 1284 x 4 KB
  zeroreg<<<1284, 256, 0, stream>>>((uint4*)(ws + 33554432));

  float* hnp = OUT + 16777216;
  float* cnp = OUT + 16777216 + 65536;
  dim3 ggrid(32, (unsigned)(Tc * 32 / 128));

  const int NCH = TT / Tc;
  for (int ch = 0; ch < NCH; ++ch) {
    int t0v = ch * Tc;
    int lastv = (ch == NCH - 1) ? 1 : 0;
    gemm128<<<ggrid, 256, 0, stream>>>(x, Wxb0, b0, G, t0v);
    void* pargs[16] = {(void*)&G,     (void*)&Wsw0, (void*)&WswP,
                       (void*)&Wsw1h, (void*)&b1,   (void*)&h0r,
                       (void*)&h1r,   (void*)&Pr,   (void*)&flg,
                       (void*)&cst,   (void*)&OUT,  (void*)&hnp,
                       (void*)&cnp,   (void*)&t0v,  (void*)&Tc,
                       (void*)&lastv};
    hipLaunchCooperativeKernel((void*)lstm_persist, dim3(4 * NA), dim3(512),
                               pargs, 0, stream);
  }
}